// Round 12
// baseline (276.867 us; speedup 1.0000x reference)
//
#include <hip/hip_runtime.h>

#define D_MODEL 256
#define NHEAD 8
#define HEAD_DIM 32
#define LEVELS 3
#define POINTS 4
#define DFF 1024
#define LQ 8400
#define BATCH 4
#define M_ROWS (BATCH * LQ)   /* 33600 */
#define NOFF 192              /* 8*3*4*2 */
#define NAW 96                /* 8*3*4 */

typedef __attribute__((ext_vector_type(8))) short bf16x8;
typedef __attribute__((ext_vector_type(4))) float f32x4;
#define MFMA16(a, b, c) __builtin_amdgcn_mfma_f32_16x16x32_bf16(a, b, c, 0, 0, 0)

// tanh-form gelu: x * sigmoid(1.5957691216*(x + 0.044715 x^3)).
__device__ __forceinline__ float gelu_fast(float x) {
    float u = 1.5957691216f * x * (1.f + 0.044715f * x * x);
    return x / (1.f + __expf(-u));
}

__device__ __forceinline__ unsigned short f2bf_rne(float f) {
    unsigned int u = __float_as_uint(f);
    u += 0x7fff + ((u >> 16) & 1);
    return (unsigned short)(u >> 16);
}

__device__ __forceinline__ float bf2f(unsigned short v) {
    return __uint_as_float(((unsigned)v) << 16);
}

// ---------------------------------------------------------------------------
// Kernel W: convert all GEMM weights f32 -> bf16 in MFMA fragment order.
// ---------------------------------------------------------------------------
__global__ __launch_bounds__(256) void k_wprep(
    const float* __restrict__ w1, const float* __restrict__ w2,
    const float* __restrict__ val_w, const float* __restrict__ out_w,
    const float* __restrict__ off_w, const float* __restrict__ aw_w,
    unsigned short* __restrict__ w1s, unsigned short* __restrict__ w2s,
    unsigned short* __restrict__ valws, unsigned short* __restrict__ outws,
    unsigned short* __restrict__ qws)
{
    int idx = blockIdx.x * 256 + threadIdx.x;   // 0 .. 262143
    int j = idx & 7, lane = (idx >> 3) & 63, rest = idx >> 9;
    int k = (lane >> 4) * 8 + j;
    int cc = lane & 15;
    {   // w1: 256x1024, NT=64
        int nt = rest & 63, kt = rest >> 6;
        w1s[idx] = f2bf_rne(w1[(size_t)(kt * 32 + k) * DFF + nt * 16 + cc]);
    }
    {   // w2: 1024x256, NT=16, KT=32
        int nt = rest & 15, kt = rest >> 4;
        w2s[idx] = f2bf_rne(w2[(size_t)(kt * 32 + k) * D_MODEL + nt * 16 + cc]);
    }
    if (idx < 65536) {   // val_w / out_w: 256x256, NT=16, KT=8
        int nt = rest & 15, kt = rest >> 4;
        valws[idx] = f2bf_rne(val_w[(size_t)(kt * 32 + k) * D_MODEL + nt * 16 + cc]);
        outws[idx] = f2bf_rne(out_w[(size_t)(kt * 32 + k) * D_MODEL + nt * 16 + cc]);
    }
    if (idx < 73728) {   // q-path: 256x288, NT=18, KT=8
        int nt = rest % 18, kt = rest / 18;
        int col = nt * 16 + cc;
        float v = (col < NOFF) ? off_w[(size_t)(kt * 32 + k) * NOFF + col]
                               : aw_w[(size_t)(kt * 32 + k) * NAW + (col - NOFF)];
        qws[idx] = f2bf_rne(v);
    }
}

// ---------------------------------------------------------------------------
// Kernel A (MFMA): value(bf16, head-major) = src@val_w+b; offs = q@off_w+b;
// aw = softmax(q@aw_w+b).  (unchanged from R11)
// ---------------------------------------------------------------------------
__global__ __launch_bounds__(256, 2) void k_prep_mfma(
    const float* __restrict__ src, const float* __restrict__ qpe,
    const unsigned short* __restrict__ valws, const float* __restrict__ val_b,
    const unsigned short* __restrict__ qws, const float* __restrict__ off_b,
    const float* __restrict__ aw_b,
    unsigned short* __restrict__ valueb, float* __restrict__ offs,
    float* __restrict__ aw)
{
    __shared__ unsigned short Xs[64 * 256];
    __shared__ unsigned short Xq[64 * 256];
    float (*awl)[NAW] = (float(*)[NAW])Xs;

    const int tid = threadIdx.x;
    const int w = tid >> 6, lane = tid & 63;
    const int g = lane >> 4, c = lane & 15;
    const int r0 = blockIdx.x * 64;

    for (int i = tid; i < 64 * 32; i += 256) {
        int row = i >> 5, c8 = (i & 31) * 8;
        const float4* ps = (const float4*)(src + (size_t)(r0 + row) * D_MODEL + c8);
        const float4* pq = (const float4*)(qpe + (size_t)(r0 + row) * D_MODEL + c8);
        float4 s0 = ps[0], s1 = ps[1];
        float4 q0 = pq[0], q1 = pq[1];
        q0.x += s0.x; q0.y += s0.y; q0.z += s0.z; q0.w += s0.w;
        q1.x += s1.x; q1.y += s1.y; q1.z += s1.z; q1.w += s1.w;
        uint4 pks, pkq;
        pks.x = (unsigned)f2bf_rne(s0.x) | ((unsigned)f2bf_rne(s0.y) << 16);
        pks.y = (unsigned)f2bf_rne(s0.z) | ((unsigned)f2bf_rne(s0.w) << 16);
        pks.z = (unsigned)f2bf_rne(s1.x) | ((unsigned)f2bf_rne(s1.y) << 16);
        pks.w = (unsigned)f2bf_rne(s1.z) | ((unsigned)f2bf_rne(s1.w) << 16);
        pkq.x = (unsigned)f2bf_rne(q0.x) | ((unsigned)f2bf_rne(q0.y) << 16);
        pkq.y = (unsigned)f2bf_rne(q0.z) | ((unsigned)f2bf_rne(q0.w) << 16);
        pkq.z = (unsigned)f2bf_rne(q1.x) | ((unsigned)f2bf_rne(q1.y) << 16);
        pkq.w = (unsigned)f2bf_rne(q1.z) | ((unsigned)f2bf_rne(q1.w) << 16);
        int di = (row * 256 + c8) ^ ((row & 7) << 3);
        *(uint4*)&Xs[di] = pks;
        *(uint4*)&Xq[di] = pkq;
    }
    __syncthreads();

    const int arow = w * 16 + c;
    const int aidx0 = (arow * 256) ^ ((arow & 7) << 3);

    {   // value GEMM: N=256, batched weight fragments per kt
        f32x4 accv[16];
        #pragma unroll
        for (int nt = 0; nt < 16; ++nt) accv[nt] = (f32x4){0.f, 0.f, 0.f, 0.f};
        #pragma unroll
        for (int kt = 0; kt < 8; ++kt) {
            bf16x8 wv[16];
            #pragma unroll
            for (int nt = 0; nt < 16; ++nt)
                wv[nt] = *(const bf16x8*)&valws[(size_t)((kt * 16 + nt) * 64 + lane) * 8];
            bf16x8 af = *(const bf16x8*)&Xs[aidx0 ^ (kt * 32 + g * 8)];
            #pragma unroll
            for (int nt = 0; nt < 16; ++nt)
                accv[nt] = MFMA16(af, wv[nt], accv[nt]);
        }
        #pragma unroll
        for (int nt = 0; nt < 16; ++nt) {
            float bias = val_b[nt * 16 + c];
            int hh = nt >> 1, dd = (nt & 1) * 16 + c;
            #pragma unroll
            for (int r = 0; r < 4; ++r) {
                int rg = r0 + w * 16 + g * 4 + r;
                int b = rg / LQ, qr = rg - b * LQ;
                valueb[(((size_t)b * NHEAD + hh) * LQ + qr) * HEAD_DIM + dd] =
                    f2bf_rne(accv[nt][r] + bias);
            }
        }
    }
    __syncthreads();

    {   // q GEMM: N=288 (12 offs tiles + 6 aw tiles), batched fragments
        f32x4 accq[18];
        #pragma unroll
        for (int nt = 0; nt < 18; ++nt) accq[nt] = (f32x4){0.f, 0.f, 0.f, 0.f};
        #pragma unroll
        for (int kt = 0; kt < 8; ++kt) {
            bf16x8 wq[18];
            #pragma unroll
            for (int nt = 0; nt < 18; ++nt)
                wq[nt] = *(const bf16x8*)&qws[(size_t)((kt * 18 + nt) * 64 + lane) * 8];
            bf16x8 af = *(const bf16x8*)&Xq[aidx0 ^ (kt * 32 + g * 8)];
            #pragma unroll
            for (int nt = 0; nt < 18; ++nt)
                accq[nt] = MFMA16(af, wq[nt], accq[nt]);
        }
        #pragma unroll
        for (int nt = 0; nt < 12; ++nt) {
            float bias = off_b[nt * 16 + c];
            #pragma unroll
            for (int r = 0; r < 4; ++r) {
                int row = w * 16 + g * 4 + r;
                offs[(size_t)(r0 + row) * NOFF + nt * 16 + c] = accq[nt][r] + bias;
            }
        }
        #pragma unroll
        for (int nt2 = 0; nt2 < 6; ++nt2) {
            float bias = aw_b[nt2 * 16 + c];
            #pragma unroll
            for (int r = 0; r < 4; ++r) {
                int row = w * 16 + g * 4 + r;
                awl[row][nt2 * 16 + c] = accq[nt2 + 12][r] + bias;
            }
        }
    }
    __syncthreads();

    for (int task = tid; task < 64 * NHEAD; task += 256) {
        int row = task >> 3, hh = task & 7;
        const float* p = &awl[row][hh * 12];
        float m = p[0];
        #pragma unroll
        for (int j = 1; j < 12; ++j) m = fmaxf(m, p[j]);
        float e[12];
        float sum = 0.f;
        #pragma unroll
        for (int j = 0; j < 12; ++j) { e[j] = __expf(p[j] - m); sum += e[j]; }
        float inv = 1.f / sum;
        float* o = &aw[(size_t)(r0 + row) * NAW + hh * 12];
        #pragma unroll
        for (int j = 0; j < 12; ++j) o[j] = e[j] * inv;
    }
}

// ---------------------------------------------------------------------------
// Kernel B: deformable bilinear sampling on bf16 head-major value (unchanged).
// ---------------------------------------------------------------------------
__global__ __launch_bounds__(256) void k_sample(
    const float* __restrict__ rp, const unsigned short* __restrict__ valueb,
    const float* __restrict__ offs, const float* __restrict__ aw,
    unsigned short* __restrict__ attnb)
{
    __shared__ int   s_x0[2][NAW];
    __shared__ int   s_y0[2][NAW];
    __shared__ float s_fx[2][NAW];
    __shared__ float s_fy[2][NAW];
    __shared__ float s_w[2][NAW];

    const int tid = threadIdx.x;
    const int row0 = blockIdx.x * 2;

    if (tid < 2 * NAW) {
        int rl = tid / NAW;
        int t  = tid - rl * NAW;
        int row = row0 + rl;
        const int h = t / 12, lp = t % 12, l = lp >> 2, p = lp & 3;
        const int dims[LEVELS] = {80, 40, 20};
        const int Wl = dims[l];
        float refx = rp[((size_t)row * LEVELS + l) * 2 + 0];
        float refy = rp[((size_t)row * LEVELS + l) * 2 + 1];
        size_t obase = (size_t)row * NOFF + (size_t)((h * LEVELS + l) * POINTS + p) * 2;
        float ox = offs[obase + 0];
        float oy = offs[obase + 1];
        float x = refx * (float)Wl + ox - 0.5f;
        float y = refy * (float)Wl + oy - 0.5f;
        float x0f = floorf(x), y0f = floorf(y);
        s_x0[rl][t] = (int)x0f;
        s_y0[rl][t] = (int)y0f;
        s_fx[rl][t] = x - x0f;
        s_fy[rl][t] = y - y0f;
        s_w[rl][t]  = aw[(size_t)row * NAW + t];
    }
    __syncthreads();

    const int rl = tid >> 7;
    const int hh = (tid >> 4) & 7;
    const int dp = tid & 15;
    const int row = row0 + rl;
    const int b = row / LQ;
    const unsigned short* vb =
        valueb + (((size_t)b * NHEAD + hh) * LQ) * HEAD_DIM + dp * 2;
    float accx = 0.f, accy = 0.f;

    #pragma unroll
    for (int lp = 0; lp < 12; ++lp) {
        const int l = lp >> 2;
        const int dims[LEVELS] = {80, 40, 20};
        const int lsis[LEVELS] = {0, 6400, 8000};
        const int W = dims[l], H = dims[l], s = lsis[l];
        const int t = hh * 12 + lp;
        int x0 = s_x0[rl][t], y0 = s_y0[rl][t];
        float fx = s_fx[rl][t], fy = s_fy[rl][t], w = s_w[rl][t];
        float w00 = (1.f - fx) * (1.f - fy);
        float w10 = fx * (1.f - fy);
        float w01 = (1.f - fx) * fy;
        float w11 = fx * fy;
        int x1 = x0 + 1, y1 = y0 + 1;
        bool xv0 = (x0 >= 0) && (x0 < W);
        bool xv1 = (x1 >= 0) && (x1 < W);
        bool yv0 = (y0 >= 0) && (y0 < H);
        bool yv1 = (y1 >= 0) && (y1 < H);
        unsigned u00 = 0, u10 = 0, u01 = 0, u11 = 0;
        if (xv0 && yv0) u00 = *(const unsigned*)&vb[(size_t)(s + y0 * W + x0) * HEAD_DIM];
        if (xv1 && yv0) u10 = *(const unsigned*)&vb[(size_t)(s + y0 * W + x1) * HEAD_DIM];
        if (xv0 && yv1) u01 = *(const unsigned*)&vb[(size_t)(s + y1 * W + x0) * HEAD_DIM];
        if (xv1 && yv1) u11 = *(const unsigned*)&vb[(size_t)(s + y1 * W + x1) * HEAD_DIM];
        float sx = w00 * bf2f((unsigned short)u00) + w10 * bf2f((unsigned short)u10)
                 + w01 * bf2f((unsigned short)u01) + w11 * bf2f((unsigned short)u11);
        float sy = w00 * bf2f((unsigned short)(u00 >> 16)) + w10 * bf2f((unsigned short)(u10 >> 16))
                 + w01 * bf2f((unsigned short)(u01 >> 16)) + w11 * bf2f((unsigned short)(u11 >> 16));
        accx += w * sx;
        accy += w * sy;
    }
    unsigned pk = (unsigned)f2bf_rne(accx) | ((unsigned)f2bf_rne(accy) << 16);
    *(unsigned*)&attnb[(size_t)row * D_MODEL + hh * HEAD_DIM + dp * 2] = pk;
}

// ---------------------------------------------------------------------------
// Kernel M: fused out-proj + LN1 + FFN + LN2.
// BM=64, CHUNK=64: per chunk each wave owns ONE GEMM1 n-tile (wf1[8]) and
// 2 kt2 W2 groups (wf2[8]) -> MFMA:load = 4:1, L2 weight traffic halved,
// FFN-phase live regs ~185 (no spill, unlike R10's wf[16] BM=64).
// Y1c XOR-swizzled stride-64 (no pad). 16 chunks, 1 barrier each.
// ---------------------------------------------------------------------------
__global__ __launch_bounds__(256, 2) void k_mlp(
    const unsigned short* __restrict__ attnb, const float* __restrict__ src,
    const unsigned short* __restrict__ outws, const float* __restrict__ out_b,
    const float* __restrict__ ln1g, const float* __restrict__ ln1b,
    const unsigned short* __restrict__ w1s, const float* __restrict__ lin1b,
    const unsigned short* __restrict__ w2s, const float* __restrict__ lin2b,
    const float* __restrict__ ln2g, const float* __restrict__ ln2b,
    float* __restrict__ out)
{
    __shared__ unsigned short Xb[64 * 256];     // 32 KB: attn bf16, then h bf16
    __shared__ unsigned short Y1c[2][64 * 64];  // 16 KB dbuf, XOR-swizzled
    __shared__ float psum[2][64][4];
    __shared__ float rowm[64], rowr[64];

    const int tid = threadIdx.x;
    const int w = tid >> 6, lane = tid & 63;
    const int g = lane >> 4, c = lane & 15;
    const int r0 = blockIdx.x * 64;

    // ---- stage attn (bf16) -> swizzled LDS ----
    for (int i = tid; i < 64 * 32; i += 256) {
        int row = i >> 5, c8 = (i & 31) * 8;
        uint4 pk = *(const uint4*)&attnb[(size_t)(r0 + row) * D_MODEL + c8];
        int di = (row * 256 + c8) ^ ((row & 7) << 3);
        *(uint4*)&Xb[di] = pk;
    }
    __syncthreads();

    {   // ---- out-proj GEMM (m=4) + bias + src residual + LN1 -> Xb ----
        f32x4 hacc[4][4];
        #pragma unroll
        for (int m = 0; m < 4; ++m)
            #pragma unroll
            for (int n = 0; n < 4; ++n)
                hacc[m][n] = (f32x4){0.f, 0.f, 0.f, 0.f};

        #pragma unroll
        for (int half = 0; half < 2; ++half) {
            bf16x8 wfa[16];
            #pragma unroll
            for (int kt = 0; kt < 4; ++kt)
                #pragma unroll
                for (int n = 0; n < 4; ++n)
                    wfa[kt * 4 + n] = *(const bf16x8*)
                        &outws[(size_t)(((half * 4 + kt) * 16 + w * 4 + n) * 64 + lane) * 8];
            #pragma unroll
            for (int kt = 0; kt < 4; ++kt) {
                bf16x8 af[4];
                #pragma unroll
                for (int m = 0; m < 4; ++m) {
                    int row = m * 16 + c;
                    af[m] = *(const bf16x8*)
                        &Xb[(row * 256 + (half * 4 + kt) * 32 + g * 8) ^ ((row & 7) << 3)];
                }
                #pragma unroll
                for (int n = 0; n < 4; ++n)
                    #pragma unroll
                    for (int m = 0; m < 4; ++m)
                        hacc[m][n] = MFMA16(af[m], wfa[kt * 4 + n], hacc[m][n]);
            }
        }
        float ob[4], lg[4], lb[4];
        #pragma unroll
        for (int n = 0; n < 4; ++n) {
            int col = w * 64 + n * 16 + c;
            ob[n] = out_b[col]; lg[n] = ln1g[col]; lb[n] = ln1b[col];
        }
        #pragma unroll
        for (int m = 0; m < 4; ++m)
            #pragma unroll
            for (int n = 0; n < 4; ++n)
                #pragma unroll
                for (int r = 0; r < 4; ++r) {
                    int row = m * 16 + g * 4 + r;
                    int col = w * 64 + n * 16 + c;
                    hacc[m][n][r] += ob[n] + src[(size_t)(r0 + row) * D_MODEL + col];
                }
        #pragma unroll
        for (int m = 0; m < 4; ++m)
            #pragma unroll
            for (int r = 0; r < 4; ++r) {
                float s = 0.f, s2 = 0.f;
                #pragma unroll
                for (int n = 0; n < 4; ++n) {
                    float v = hacc[m][n][r];
                    s += v; s2 += v * v;
                }
                #pragma unroll
                for (int mask = 1; mask < 16; mask <<= 1) {
                    s  += __shfl_xor(s, mask);
                    s2 += __shfl_xor(s2, mask);
                }
                if (c == 0) {
                    int row = m * 16 + g * 4 + r;
                    psum[0][row][w] = s;
                    psum[1][row][w] = s2;
                }
            }
        __syncthreads();
        if (tid < 64) {
            float s  = psum[0][tid][0] + psum[0][tid][1] + psum[0][tid][2] + psum[0][tid][3];
            float s2 = psum[1][tid][0] + psum[1][tid][1] + psum[1][tid][2] + psum[1][tid][3];
            float mn = s * (1.f / D_MODEL);
            float var = s2 * (1.f / D_MODEL) - mn * mn;
            rowm[tid] = mn;
            rowr[tid] = rsqrtf(var + 1e-5f);
        }
        __syncthreads();
        #pragma unroll
        for (int m = 0; m < 4; ++m)
            #pragma unroll
            for (int n = 0; n < 4; ++n)
                #pragma unroll
                for (int r = 0; r < 4; ++r) {
                    int row = m * 16 + g * 4 + r;
                    int col = w * 64 + n * 16 + c;
                    float v = (hacc[m][n][r] - rowm[row]) * rowr[row] * lg[n] + lb[n];
                    Xb[(row * 256 + col) ^ ((row & 7) << 3)] = f2bf_rne(v);
                }
    }
    __syncthreads();

    // ---- FFN: 16 chunks of 64 cols, wf1[8]/wf2[8], 1 barrier/chunk ----
    f32x4 acc2[4][4];
    #pragma unroll
    for (int m = 0; m < 4; ++m)
        #pragma unroll
        for (int n = 0; n < 4; ++n)
            acc2[m][n] = (f32x4){0.f, 0.f, 0.f, 0.f};

    bf16x8 wf1[8];   // W1 frags: kt 0..7, nt = ch*4 + w
    bf16x8 wf2[8];   // W2 frags: kt2 0..1 (global ch*2+kt2), n = w*4..+4

    #pragma unroll
    for (int kt = 0; kt < 8; ++kt)
        wf1[kt] = *(const bf16x8*)&w1s[(size_t)((kt * 64 + w) * 64 + lane) * 8];
    {   // GEMM1 chunk 0 -> Y1c[0]
        f32x4 acc1[4];
        #pragma unroll
        for (int m = 0; m < 4; ++m) acc1[m] = (f32x4){0.f, 0.f, 0.f, 0.f};
        #pragma unroll
        for (int kt = 0; kt < 8; ++kt) {
            bf16x8 af[4];
            #pragma unroll
            for (int m = 0; m < 4; ++m) {
                int row = m * 16 + c;
                af[m] = *(const bf16x8*)&Xb[(row * 256 + kt * 32 + g * 8) ^ ((row & 7) << 3)];
            }
            #pragma unroll
            for (int m = 0; m < 4; ++m)
                acc1[m] = MFMA16(af[m], wf1[kt], acc1[m]);
        }
        // issue wf2(0) and wf1(1) — land under gelu + barrier
        #pragma unroll
        for (int kt2 = 0; kt2 < 2; ++kt2)
            #pragma unroll
            for (int n = 0; n < 4; ++n)
                wf2[kt2 * 4 + n] = *(const bf16x8*)
                    &w2s[(size_t)((kt2 * 16 + w * 4 + n) * 64 + lane) * 8];
        #pragma unroll
        for (int kt = 0; kt < 8; ++kt)
            wf1[kt] = *(const bf16x8*)&w1s[(size_t)((kt * 64 + 4 + w) * 64 + lane) * 8];
        float bias = lin1b[w * 16 + c];
        #pragma unroll
        for (int m = 0; m < 4; ++m)
            #pragma unroll
            for (int r = 0; r < 4; ++r) {
                int row = m * 16 + g * 4 + r;
                Y1c[0][(row * 64 + w * 16 + c) ^ ((row & 7) << 3)] =
                    f2bf_rne(gelu_fast(acc1[m][r] + bias));
            }
    }
    __syncthreads();

    for (int ch = 0; ch < 16; ++ch) {
        // GEMM2(ch): W2 rows [ch*64,+64) -> acc2
        const unsigned short* yb = Y1c[ch & 1];
        #pragma unroll
        for (int kt2 = 0; kt2 < 2; ++kt2) {
            bf16x8 a2[4];
            #pragma unroll
            for (int m = 0; m < 4; ++m) {
                int row = m * 16 + c;
                a2[m] = *(const bf16x8*)&yb[(row * 64 + kt2 * 32 + g * 8) ^ ((row & 7) << 3)];
            }
            #pragma unroll
            for (int n = 0; n < 4; ++n)
                #pragma unroll
                for (int m = 0; m < 4; ++m)
                    acc2[m][n] = MFMA16(a2[m], wf2[kt2 * 4 + n], acc2[m][n]);
        }
        if (ch < 15) {
            // issue wf2(ch+1) — after its last use above
            #pragma unroll
            for (int kt2 = 0; kt2 < 2; ++kt2)
                #pragma unroll
                for (int n = 0; n < 4; ++n)
                    wf2[kt2 * 4 + n] = *(const bf16x8*)
                        &w2s[(size_t)((((ch + 1) * 2 + kt2) * 16 + w * 4 + n) * 64 + lane) * 8];
            // GEMM1(ch+1) using wf1 (issued previous iteration)
            f32x4 acc1[4];
            #pragma unroll
            for (int m = 0; m < 4; ++m) acc1[m] = (f32x4){0.f, 0.f, 0.f, 0.f};
            #pragma unroll
            for (int kt = 0; kt < 8; ++kt) {
                bf16x8 af[4];
                #pragma unroll
                for (int m = 0; m < 4; ++m) {
                    int row = m * 16 + c;
                    af[m] = *(const bf16x8*)&Xb[(row * 256 + kt * 32 + g * 8) ^ ((row & 7) << 3)];
                }
                #pragma unroll
                for (int m = 0; m < 4; ++m)
                    acc1[m] = MFMA16(af[m], wf1[kt], acc1[m]);
            }
            // issue wf1(ch+2)
            if (ch < 14) {
                #pragma unroll
                for (int kt = 0; kt < 8; ++kt)
                    wf1[kt] = *(const bf16x8*)
                        &w1s[(size_t)((kt * 64 + (ch + 2) * 4 + w) * 64 + lane) * 8];
            }
            float bias = lin1b[(ch + 1) * 64 + w * 16 + c];
            unsigned short* yw = Y1c[(ch + 1) & 1];
            #pragma unroll
            for (int m = 0; m < 4; ++m)
                #pragma unroll
                for (int r = 0; r < 4; ++r) {
                    int row = m * 16 + g * 4 + r;
                    yw[(row * 64 + w * 16 + c) ^ ((row & 7) << 3)] =
                        f2bf_rne(gelu_fast(acc1[m][r] + bias));
                }
        }
        __syncthreads();
    }

    // ---- epilogue: + lin2 bias + h residual (bf16 from Xb), LN2, store ----
    float b2c[4], g2c[4], bb2c[4];
    #pragma unroll
    for (int n = 0; n < 4; ++n) {
        int col = w * 64 + n * 16 + c;
        b2c[n] = lin2b[col]; g2c[n] = ln2g[col]; bb2c[n] = ln2b[col];
    }
    #pragma unroll
    for (int m = 0; m < 4; ++m)
        #pragma unroll
        for (int n = 0; n < 4; ++n)
            #pragma unroll
            for (int r = 0; r < 4; ++r) {
                int row = m * 16 + g * 4 + r;
                int col = w * 64 + n * 16 + c;
                float hres = bf2f(Xb[(row * 256 + col) ^ ((row & 7) << 3)]);
                acc2[m][n][r] += b2c[n] + hres;
            }
    #pragma unroll
    for (int m = 0; m < 4; ++m)
        #pragma unroll
        for (int r = 0; r < 4; ++r) {
            float s = 0.f, s2 = 0.f;
            #pragma unroll
            for (int n = 0; n < 4; ++n) {
                float v = acc2[m][n][r];
                s += v; s2 += v * v;
            }
            #pragma unroll
            for (int mask = 1; mask < 16; mask <<= 1) {
                s  += __shfl_xor(s, mask);
                s2 += __shfl_xor(s2, mask);
            }
            if (c == 0) {
                int row = m * 16 + g * 4 + r;
                psum[0][row][w] = s;
                psum[1][row][w] = s2;
            }
        }
    __syncthreads();
    if (tid < 64) {
        float s  = psum[0][tid][0] + psum[0][tid][1] + psum[0][tid][2] + psum[0][tid][3];
        float s2 = psum[1][tid][0] + psum[1][tid][1] + psum[1][tid][2] + psum[1][tid][3];
        float mn = s * (1.f / D_MODEL);
        float var = s2 * (1.f / D_MODEL) - mn * mn;
        rowm[tid] = mn;
        rowr[tid] = rsqrtf(var + 1e-5f);
    }
    __syncthreads();
    #pragma unroll
    for (int m = 0; m < 4; ++m)
        #pragma unroll
        for (int n = 0; n < 4; ++n)
            #pragma unroll
            for (int r = 0; r < 4; ++r) {
                int row = m * 16 + g * 4 + r;
                int col = w * 64 + n * 16 + c;
                float v = (acc2[m][n][r] - rowm[row]) * rowr[row] * g2c[n] + bb2c[n];
                out[(size_t)(r0 + row) * D_MODEL + col] = v;
            }
}

// ---------------------------------------------------------------------------
extern "C" void kernel_launch(void* const* d_in, const int* in_sizes, int n_in,
                              void* d_out, int out_size, void* d_ws, size_t ws_size,
                              hipStream_t stream) {
    const float* src   = (const float*)d_in[0];
    const float* rp    = (const float*)d_in[1];
    const float* qpe   = (const float*)d_in[2];
    const float* off_w = (const float*)d_in[5];
    const float* off_b = (const float*)d_in[6];
    const float* aw_w  = (const float*)d_in[7];
    const float* aw_b  = (const float*)d_in[8];
    const float* val_w = (const float*)d_in[9];
    const float* val_b = (const float*)d_in[10];
    const float* out_w = (const float*)d_in[11];
    const float* out_b = (const float*)d_in[12];
    const float* w1    = (const float*)d_in[13];
    const float* b1    = (const float*)d_in[14];
    const float* w2    = (const float*)d_in[15];
    const float* b2    = (const float*)d_in[16];
    const float* ln1g  = (const float*)d_in[17];
    const float* ln1b  = (const float*)d_in[18];
    const float* ln2g  = (const float*)d_in[19];
    const float* ln2b  = (const float*)d_in[20];
    float* out = (float*)d_out;

    float* ws    = (float*)d_ws;
    float* value = ws;                                   // M*256 region (bf16 used)
    float* offs  = value + (size_t)M_ROWS * D_MODEL;     // M*192
    float* aw    = offs + (size_t)M_ROWS * NOFF;         // M*96
    float* attn  = aw + (size_t)M_ROWS * NAW;            // M*256 region (bf16 used)
    unsigned short* valueb = (unsigned short*)value;     // [b][h][Lq][32] bf16
    unsigned short* attnb  = (unsigned short*)attn;      // [row][256] bf16
    unsigned short* w1s   = (unsigned short*)(attn + (size_t)M_ROWS * D_MODEL);
    unsigned short* w2s   = w1s + 262144;
    unsigned short* valws = w2s + 262144;                // 65536
    unsigned short* outws = valws + 65536;               // 65536
    unsigned short* qws   = outws + 65536;               // 73728

    k_wprep<<<1024, 256, 0, stream>>>(w1, w2, val_w, out_w, off_w, aw_w,
                                      w1s, w2s, valws, outws, qws);
    k_prep_mfma<<<M_ROWS / 64, 256, 0, stream>>>(src, qpe, valws, val_b,
                                                 qws, off_b, aw_b,
                                                 valueb, offs, aw);
    k_sample<<<M_ROWS / 2, 256, 0, stream>>>(rp, valueb, offs, aw, attnb);
    k_mlp<<<M_ROWS / 64, 256, 0, stream>>>(attnb, src, outws, out_b,
                                           ln1g, ln1b, w1s, b1, w2s, b2,
                                           ln2g, ln2b, out);
}

// Round 13
// 252.030 us; speedup vs baseline: 1.0985x; 1.0985x over previous
//
#include <hip/hip_runtime.h>

#define D_MODEL 256
#define NHEAD 8
#define HEAD_DIM 32
#define LEVELS 3
#define POINTS 4
#define DFF 1024
#define LQ 8400
#define BATCH 4
#define M_ROWS (BATCH * LQ)   /* 33600 */
#define NOFF 192              /* 8*3*4*2 */
#define NAW 96                /* 8*3*4 */

typedef __attribute__((ext_vector_type(8))) short bf16x8;
typedef __attribute__((ext_vector_type(4))) float f32x4;
#define MFMA16(a, b, c) __builtin_amdgcn_mfma_f32_16x16x32_bf16(a, b, c, 0, 0, 0)

// tanh-form gelu: x * sigmoid(1.5957691216*(x + 0.044715 x^3)).
__device__ __forceinline__ float gelu_fast(float x) {
    float u = 1.5957691216f * x * (1.f + 0.044715f * x * x);
    return x / (1.f + __expf(-u));
}

__device__ __forceinline__ unsigned short f2bf_rne(float f) {
    unsigned int u = __float_as_uint(f);
    u += 0x7fff + ((u >> 16) & 1);
    return (unsigned short)(u >> 16);
}

__device__ __forceinline__ float bf2f(unsigned short v) {
    return __uint_as_float(((unsigned)v) << 16);
}

// ---------------------------------------------------------------------------
// Kernel W: convert all GEMM weights f32 -> bf16 in MFMA fragment order.
// ---------------------------------------------------------------------------
__global__ __launch_bounds__(256) void k_wprep(
    const float* __restrict__ w1, const float* __restrict__ w2,
    const float* __restrict__ val_w, const float* __restrict__ out_w,
    const float* __restrict__ off_w, const float* __restrict__ aw_w,
    unsigned short* __restrict__ w1s, unsigned short* __restrict__ w2s,
    unsigned short* __restrict__ valws, unsigned short* __restrict__ outws,
    unsigned short* __restrict__ qws)
{
    int idx = blockIdx.x * 256 + threadIdx.x;   // 0 .. 262143
    int j = idx & 7, lane = (idx >> 3) & 63, rest = idx >> 9;
    int k = (lane >> 4) * 8 + j;
    int cc = lane & 15;
    {   // w1: 256x1024, NT=64
        int nt = rest & 63, kt = rest >> 6;
        w1s[idx] = f2bf_rne(w1[(size_t)(kt * 32 + k) * DFF + nt * 16 + cc]);
    }
    {   // w2: 1024x256, NT=16, KT=32
        int nt = rest & 15, kt = rest >> 4;
        w2s[idx] = f2bf_rne(w2[(size_t)(kt * 32 + k) * D_MODEL + nt * 16 + cc]);
    }
    if (idx < 65536) {   // val_w / out_w: 256x256, NT=16, KT=8
        int nt = rest & 15, kt = rest >> 4;
        valws[idx] = f2bf_rne(val_w[(size_t)(kt * 32 + k) * D_MODEL + nt * 16 + cc]);
        outws[idx] = f2bf_rne(out_w[(size_t)(kt * 32 + k) * D_MODEL + nt * 16 + cc]);
    }
    if (idx < 73728) {   // q-path: 256x288, NT=18, KT=8
        int nt = rest % 18, kt = rest / 18;
        int col = nt * 16 + cc;
        float v = (col < NOFF) ? off_w[(size_t)(kt * 32 + k) * NOFF + col]
                               : aw_w[(size_t)(kt * 32 + k) * NAW + (col - NOFF)];
        qws[idx] = f2bf_rne(v);
    }
}

// ---------------------------------------------------------------------------
// Kernel A (MFMA): value(bf16, head-major) = src@val_w+b; offs = q@off_w+b;
// aw = softmax(q@aw_w+b).  (unchanged from R11)
// ---------------------------------------------------------------------------
__global__ __launch_bounds__(256, 2) void k_prep_mfma(
    const float* __restrict__ src, const float* __restrict__ qpe,
    const unsigned short* __restrict__ valws, const float* __restrict__ val_b,
    const unsigned short* __restrict__ qws, const float* __restrict__ off_b,
    const float* __restrict__ aw_b,
    unsigned short* __restrict__ valueb, float* __restrict__ offs,
    float* __restrict__ aw)
{
    __shared__ unsigned short Xs[64 * 256];
    __shared__ unsigned short Xq[64 * 256];
    float (*awl)[NAW] = (float(*)[NAW])Xs;

    const int tid = threadIdx.x;
    const int w = tid >> 6, lane = tid & 63;
    const int g = lane >> 4, c = lane & 15;
    const int r0 = blockIdx.x * 64;

    for (int i = tid; i < 64 * 32; i += 256) {
        int row = i >> 5, c8 = (i & 31) * 8;
        const float4* ps = (const float4*)(src + (size_t)(r0 + row) * D_MODEL + c8);
        const float4* pq = (const float4*)(qpe + (size_t)(r0 + row) * D_MODEL + c8);
        float4 s0 = ps[0], s1 = ps[1];
        float4 q0 = pq[0], q1 = pq[1];
        q0.x += s0.x; q0.y += s0.y; q0.z += s0.z; q0.w += s0.w;
        q1.x += s1.x; q1.y += s1.y; q1.z += s1.z; q1.w += s1.w;
        uint4 pks, pkq;
        pks.x = (unsigned)f2bf_rne(s0.x) | ((unsigned)f2bf_rne(s0.y) << 16);
        pks.y = (unsigned)f2bf_rne(s0.z) | ((unsigned)f2bf_rne(s0.w) << 16);
        pks.z = (unsigned)f2bf_rne(s1.x) | ((unsigned)f2bf_rne(s1.y) << 16);
        pks.w = (unsigned)f2bf_rne(s1.z) | ((unsigned)f2bf_rne(s1.w) << 16);
        pkq.x = (unsigned)f2bf_rne(q0.x) | ((unsigned)f2bf_rne(q0.y) << 16);
        pkq.y = (unsigned)f2bf_rne(q0.z) | ((unsigned)f2bf_rne(q0.w) << 16);
        pkq.z = (unsigned)f2bf_rne(q1.x) | ((unsigned)f2bf_rne(q1.y) << 16);
        pkq.w = (unsigned)f2bf_rne(q1.z) | ((unsigned)f2bf_rne(q1.w) << 16);
        int di = (row * 256 + c8) ^ ((row & 7) << 3);
        *(uint4*)&Xs[di] = pks;
        *(uint4*)&Xq[di] = pkq;
    }
    __syncthreads();

    const int arow = w * 16 + c;
    const int aidx0 = (arow * 256) ^ ((arow & 7) << 3);

    {   // value GEMM: N=256, batched weight fragments per kt
        f32x4 accv[16];
        #pragma unroll
        for (int nt = 0; nt < 16; ++nt) accv[nt] = (f32x4){0.f, 0.f, 0.f, 0.f};
        #pragma unroll
        for (int kt = 0; kt < 8; ++kt) {
            bf16x8 wv[16];
            #pragma unroll
            for (int nt = 0; nt < 16; ++nt)
                wv[nt] = *(const bf16x8*)&valws[(size_t)((kt * 16 + nt) * 64 + lane) * 8];
            bf16x8 af = *(const bf16x8*)&Xs[aidx0 ^ (kt * 32 + g * 8)];
            #pragma unroll
            for (int nt = 0; nt < 16; ++nt)
                accv[nt] = MFMA16(af, wv[nt], accv[nt]);
        }
        #pragma unroll
        for (int nt = 0; nt < 16; ++nt) {
            float bias = val_b[nt * 16 + c];
            int hh = nt >> 1, dd = (nt & 1) * 16 + c;
            #pragma unroll
            for (int r = 0; r < 4; ++r) {
                int rg = r0 + w * 16 + g * 4 + r;
                int b = rg / LQ, qr = rg - b * LQ;
                valueb[(((size_t)b * NHEAD + hh) * LQ + qr) * HEAD_DIM + dd] =
                    f2bf_rne(accv[nt][r] + bias);
            }
        }
    }
    __syncthreads();

    {   // q GEMM: N=288 (12 offs tiles + 6 aw tiles), batched fragments
        f32x4 accq[18];
        #pragma unroll
        for (int nt = 0; nt < 18; ++nt) accq[nt] = (f32x4){0.f, 0.f, 0.f, 0.f};
        #pragma unroll
        for (int kt = 0; kt < 8; ++kt) {
            bf16x8 wq[18];
            #pragma unroll
            for (int nt = 0; nt < 18; ++nt)
                wq[nt] = *(const bf16x8*)&qws[(size_t)((kt * 18 + nt) * 64 + lane) * 8];
            bf16x8 af = *(const bf16x8*)&Xq[aidx0 ^ (kt * 32 + g * 8)];
            #pragma unroll
            for (int nt = 0; nt < 18; ++nt)
                accq[nt] = MFMA16(af, wq[nt], accq[nt]);
        }
        #pragma unroll
        for (int nt = 0; nt < 12; ++nt) {
            float bias = off_b[nt * 16 + c];
            #pragma unroll
            for (int r = 0; r < 4; ++r) {
                int row = w * 16 + g * 4 + r;
                offs[(size_t)(r0 + row) * NOFF + nt * 16 + c] = accq[nt][r] + bias;
            }
        }
        #pragma unroll
        for (int nt2 = 0; nt2 < 6; ++nt2) {
            float bias = aw_b[nt2 * 16 + c];
            #pragma unroll
            for (int r = 0; r < 4; ++r) {
                int row = w * 16 + g * 4 + r;
                awl[row][nt2 * 16 + c] = accq[nt2 + 12][r] + bias;
            }
        }
    }
    __syncthreads();

    for (int task = tid; task < 64 * NHEAD; task += 256) {
        int row = task >> 3, hh = task & 7;
        const float* p = &awl[row][hh * 12];
        float m = p[0];
        #pragma unroll
        for (int j = 1; j < 12; ++j) m = fmaxf(m, p[j]);
        float e[12];
        float sum = 0.f;
        #pragma unroll
        for (int j = 0; j < 12; ++j) { e[j] = __expf(p[j] - m); sum += e[j]; }
        float inv = 1.f / sum;
        float* o = &aw[(size_t)(r0 + row) * NAW + hh * 12];
        #pragma unroll
        for (int j = 0; j < 12; ++j) o[j] = e[j] * inv;
    }
}

// ---------------------------------------------------------------------------
// Kernel B: deformable bilinear sampling on bf16 head-major value (unchanged).
// ---------------------------------------------------------------------------
__global__ __launch_bounds__(256) void k_sample(
    const float* __restrict__ rp, const unsigned short* __restrict__ valueb,
    const float* __restrict__ offs, const float* __restrict__ aw,
    unsigned short* __restrict__ attnb)
{
    __shared__ int   s_x0[2][NAW];
    __shared__ int   s_y0[2][NAW];
    __shared__ float s_fx[2][NAW];
    __shared__ float s_fy[2][NAW];
    __shared__ float s_w[2][NAW];

    const int tid = threadIdx.x;
    const int row0 = blockIdx.x * 2;

    if (tid < 2 * NAW) {
        int rl = tid / NAW;
        int t  = tid - rl * NAW;
        int row = row0 + rl;
        const int h = t / 12, lp = t % 12, l = lp >> 2, p = lp & 3;
        const int dims[LEVELS] = {80, 40, 20};
        const int Wl = dims[l];
        float refx = rp[((size_t)row * LEVELS + l) * 2 + 0];
        float refy = rp[((size_t)row * LEVELS + l) * 2 + 1];
        size_t obase = (size_t)row * NOFF + (size_t)((h * LEVELS + l) * POINTS + p) * 2;
        float ox = offs[obase + 0];
        float oy = offs[obase + 1];
        float x = refx * (float)Wl + ox - 0.5f;
        float y = refy * (float)Wl + oy - 0.5f;
        float x0f = floorf(x), y0f = floorf(y);
        s_x0[rl][t] = (int)x0f;
        s_y0[rl][t] = (int)y0f;
        s_fx[rl][t] = x - x0f;
        s_fy[rl][t] = y - y0f;
        s_w[rl][t]  = aw[(size_t)row * NAW + t];
    }
    __syncthreads();

    const int rl = tid >> 7;
    const int hh = (tid >> 4) & 7;
    const int dp = tid & 15;
    const int row = row0 + rl;
    const int b = row / LQ;
    const unsigned short* vb =
        valueb + (((size_t)b * NHEAD + hh) * LQ) * HEAD_DIM + dp * 2;
    float accx = 0.f, accy = 0.f;

    #pragma unroll
    for (int lp = 0; lp < 12; ++lp) {
        const int l = lp >> 2;
        const int dims[LEVELS] = {80, 40, 20};
        const int lsis[LEVELS] = {0, 6400, 8000};
        const int W = dims[l], H = dims[l], s = lsis[l];
        const int t = hh * 12 + lp;
        int x0 = s_x0[rl][t], y0 = s_y0[rl][t];
        float fx = s_fx[rl][t], fy = s_fy[rl][t], w = s_w[rl][t];
        float w00 = (1.f - fx) * (1.f - fy);
        float w10 = fx * (1.f - fy);
        float w01 = (1.f - fx) * fy;
        float w11 = fx * fy;
        int x1 = x0 + 1, y1 = y0 + 1;
        bool xv0 = (x0 >= 0) && (x0 < W);
        bool xv1 = (x1 >= 0) && (x1 < W);
        bool yv0 = (y0 >= 0) && (y0 < H);
        bool yv1 = (y1 >= 0) && (y1 < H);
        unsigned u00 = 0, u10 = 0, u01 = 0, u11 = 0;
        if (xv0 && yv0) u00 = *(const unsigned*)&vb[(size_t)(s + y0 * W + x0) * HEAD_DIM];
        if (xv1 && yv0) u10 = *(const unsigned*)&vb[(size_t)(s + y0 * W + x1) * HEAD_DIM];
        if (xv0 && yv1) u01 = *(const unsigned*)&vb[(size_t)(s + y1 * W + x0) * HEAD_DIM];
        if (xv1 && yv1) u11 = *(const unsigned*)&vb[(size_t)(s + y1 * W + x1) * HEAD_DIM];
        float sx = w00 * bf2f((unsigned short)u00) + w10 * bf2f((unsigned short)u10)
                 + w01 * bf2f((unsigned short)u01) + w11 * bf2f((unsigned short)u11);
        float sy = w00 * bf2f((unsigned short)(u00 >> 16)) + w10 * bf2f((unsigned short)(u10 >> 16))
                 + w01 * bf2f((unsigned short)(u01 >> 16)) + w11 * bf2f((unsigned short)(u11 >> 16));
        accx += w * sx;
        accy += w * sy;
    }
    unsigned pk = (unsigned)f2bf_rne(accx) | ((unsigned)f2bf_rne(accy) << 16);
    *(unsigned*)&attnb[(size_t)row * D_MODEL + hh * HEAD_DIM + dp * 2] = pk;
}

// ---------------------------------------------------------------------------
// Kernel M: fused out-proj + LN1 + FFN + LN2.
// BM=32 (m=2, the no-spill geometry) + CHUNK=64 (wf1[8]+wf2[8] = 64 VGPR of
// weight frags, half of R11) + launch_bounds(256,3) -> target 3 blocks/CU.
// Y1c XOR-swizzled stride-64 dbuf (verified in R12). 16 chunks, 1 barrier ea.
// ---------------------------------------------------------------------------
__global__ __launch_bounds__(256, 3) void k_mlp(
    const unsigned short* __restrict__ attnb, const float* __restrict__ src,
    const unsigned short* __restrict__ outws, const float* __restrict__ out_b,
    const float* __restrict__ ln1g, const float* __restrict__ ln1b,
    const unsigned short* __restrict__ w1s, const float* __restrict__ lin1b,
    const unsigned short* __restrict__ w2s, const float* __restrict__ lin2b,
    const float* __restrict__ ln2g, const float* __restrict__ ln2b,
    float* __restrict__ out)
{
    __shared__ unsigned short Xb[32 * 256];     // 16 KB: attn bf16, then h bf16
    __shared__ unsigned short Y1c[2][32 * 64];  // 8 KB dbuf, XOR-swizzled
    __shared__ float psum[2][32][4];
    __shared__ float rowm[32], rowr[32];

    const int tid = threadIdx.x;
    const int w = tid >> 6, lane = tid & 63;
    const int g = lane >> 4, c = lane & 15;
    const int r0 = blockIdx.x * 32;

    // ---- stage attn (bf16) -> swizzled LDS ----
    for (int i = tid; i < 32 * 32; i += 256) {
        int row = i >> 5, c8 = (i & 31) * 8;
        uint4 pk = *(const uint4*)&attnb[(size_t)(r0 + row) * D_MODEL + c8];
        int di = (row * 256 + c8) ^ ((row & 7) << 3);
        *(uint4*)&Xb[di] = pk;
    }
    __syncthreads();

    {   // ---- out-proj GEMM (weights in 2 batches of 16) + LN1 -> Xb ----
        f32x4 hacc[2][4];
        #pragma unroll
        for (int m = 0; m < 2; ++m)
            #pragma unroll
            for (int n = 0; n < 4; ++n)
                hacc[m][n] = (f32x4){0.f, 0.f, 0.f, 0.f};

        #pragma unroll
        for (int half = 0; half < 2; ++half) {
            bf16x8 wfa[16];
            #pragma unroll
            for (int kt = 0; kt < 4; ++kt)
                #pragma unroll
                for (int n = 0; n < 4; ++n)
                    wfa[kt * 4 + n] = *(const bf16x8*)
                        &outws[(size_t)(((half * 4 + kt) * 16 + w * 4 + n) * 64 + lane) * 8];
            #pragma unroll
            for (int kt = 0; kt < 4; ++kt) {
                bf16x8 af[2];
                #pragma unroll
                for (int m = 0; m < 2; ++m) {
                    int row = m * 16 + c;
                    af[m] = *(const bf16x8*)
                        &Xb[(row * 256 + (half * 4 + kt) * 32 + g * 8) ^ ((row & 7) << 3)];
                }
                #pragma unroll
                for (int n = 0; n < 4; ++n)
                    #pragma unroll
                    for (int m = 0; m < 2; ++m)
                        hacc[m][n] = MFMA16(af[m], wfa[kt * 4 + n], hacc[m][n]);
            }
        }
        float ob[4], lg[4], lb[4];
        #pragma unroll
        for (int n = 0; n < 4; ++n) {
            int col = w * 64 + n * 16 + c;
            ob[n] = out_b[col]; lg[n] = ln1g[col]; lb[n] = ln1b[col];
        }
        #pragma unroll
        for (int m = 0; m < 2; ++m)
            #pragma unroll
            for (int n = 0; n < 4; ++n)
                #pragma unroll
                for (int r = 0; r < 4; ++r) {
                    int row = m * 16 + g * 4 + r;
                    int col = w * 64 + n * 16 + c;
                    hacc[m][n][r] += ob[n] + src[(size_t)(r0 + row) * D_MODEL + col];
                }
        #pragma unroll
        for (int m = 0; m < 2; ++m)
            #pragma unroll
            for (int r = 0; r < 4; ++r) {
                float s = 0.f, s2 = 0.f;
                #pragma unroll
                for (int n = 0; n < 4; ++n) {
                    float v = hacc[m][n][r];
                    s += v; s2 += v * v;
                }
                #pragma unroll
                for (int mask = 1; mask < 16; mask <<= 1) {
                    s  += __shfl_xor(s, mask);
                    s2 += __shfl_xor(s2, mask);
                }
                if (c == 0) {
                    int row = m * 16 + g * 4 + r;
                    psum[0][row][w] = s;
                    psum[1][row][w] = s2;
                }
            }
        __syncthreads();
        if (tid < 32) {
            float s  = psum[0][tid][0] + psum[0][tid][1] + psum[0][tid][2] + psum[0][tid][3];
            float s2 = psum[1][tid][0] + psum[1][tid][1] + psum[1][tid][2] + psum[1][tid][3];
            float mn = s * (1.f / D_MODEL);
            float var = s2 * (1.f / D_MODEL) - mn * mn;
            rowm[tid] = mn;
            rowr[tid] = rsqrtf(var + 1e-5f);
        }
        __syncthreads();
        #pragma unroll
        for (int m = 0; m < 2; ++m)
            #pragma unroll
            for (int n = 0; n < 4; ++n)
                #pragma unroll
                for (int r = 0; r < 4; ++r) {
                    int row = m * 16 + g * 4 + r;
                    int col = w * 64 + n * 16 + c;
                    float v = (hacc[m][n][r] - rowm[row]) * rowr[row] * lg[n] + lb[n];
                    Xb[(row * 256 + col) ^ ((row & 7) << 3)] = f2bf_rne(v);
                }
    }
    __syncthreads();

    // ---- FFN: 16 chunks of 64 cols, wf1[8]/wf2[8], 1 barrier/chunk ----
    f32x4 acc2[2][4];
    #pragma unroll
    for (int m = 0; m < 2; ++m)
        #pragma unroll
        for (int n = 0; n < 4; ++n)
            acc2[m][n] = (f32x4){0.f, 0.f, 0.f, 0.f};

    bf16x8 wf1[8];   // W1 frags: kt 0..7, nt = ch*4 + w
    bf16x8 wf2[8];   // W2 frags: kt2 0..1 (global ch*2+kt2), n = w*4..+4

    #pragma unroll
    for (int kt = 0; kt < 8; ++kt)
        wf1[kt] = *(const bf16x8*)&w1s[(size_t)((kt * 64 + w) * 64 + lane) * 8];
    {   // GEMM1 chunk 0 -> Y1c[0]
        f32x4 acc1[2];
        #pragma unroll
        for (int m = 0; m < 2; ++m) acc1[m] = (f32x4){0.f, 0.f, 0.f, 0.f};
        #pragma unroll
        for (int kt = 0; kt < 8; ++kt) {
            bf16x8 af[2];
            #pragma unroll
            for (int m = 0; m < 2; ++m) {
                int row = m * 16 + c;
                af[m] = *(const bf16x8*)&Xb[(row * 256 + kt * 32 + g * 8) ^ ((row & 7) << 3)];
            }
            #pragma unroll
            for (int m = 0; m < 2; ++m)
                acc1[m] = MFMA16(af[m], wf1[kt], acc1[m]);
        }
        // issue wf2(0) and wf1(1) — land under gelu + barrier
        #pragma unroll
        for (int kt2 = 0; kt2 < 2; ++kt2)
            #pragma unroll
            for (int n = 0; n < 4; ++n)
                wf2[kt2 * 4 + n] = *(const bf16x8*)
                    &w2s[(size_t)((kt2 * 16 + w * 4 + n) * 64 + lane) * 8];
        #pragma unroll
        for (int kt = 0; kt < 8; ++kt)
            wf1[kt] = *(const bf16x8*)&w1s[(size_t)((kt * 64 + 4 + w) * 64 + lane) * 8];
        float bias = lin1b[w * 16 + c];
        #pragma unroll
        for (int m = 0; m < 2; ++m)
            #pragma unroll
            for (int r = 0; r < 4; ++r) {
                int row = m * 16 + g * 4 + r;
                Y1c[0][(row * 64 + w * 16 + c) ^ ((row & 7) << 3)] =
                    f2bf_rne(gelu_fast(acc1[m][r] + bias));
            }
    }
    __syncthreads();

    for (int ch = 0; ch < 16; ++ch) {
        // GEMM2(ch): W2 rows [ch*64,+64) -> acc2
        const unsigned short* yb = Y1c[ch & 1];
        #pragma unroll
        for (int kt2 = 0; kt2 < 2; ++kt2) {
            bf16x8 a2[2];
            #pragma unroll
            for (int m = 0; m < 2; ++m) {
                int row = m * 16 + c;
                a2[m] = *(const bf16x8*)&yb[(row * 64 + kt2 * 32 + g * 8) ^ ((row & 7) << 3)];
            }
            #pragma unroll
            for (int n = 0; n < 4; ++n)
                #pragma unroll
                for (int m = 0; m < 2; ++m)
                    acc2[m][n] = MFMA16(a2[m], wf2[kt2 * 4 + n], acc2[m][n]);
        }
        if (ch < 15) {
            // issue wf2(ch+1) — after its last use above
            #pragma unroll
            for (int kt2 = 0; kt2 < 2; ++kt2)
                #pragma unroll
                for (int n = 0; n < 4; ++n)
                    wf2[kt2 * 4 + n] = *(const bf16x8*)
                        &w2s[(size_t)((((ch + 1) * 2 + kt2) * 16 + w * 4 + n) * 64 + lane) * 8];
            // GEMM1(ch+1) using wf1 (issued previous iteration)
            f32x4 acc1[2];
            #pragma unroll
            for (int m = 0; m < 2; ++m) acc1[m] = (f32x4){0.f, 0.f, 0.f, 0.f};
            #pragma unroll
            for (int kt = 0; kt < 8; ++kt) {
                bf16x8 af[2];
                #pragma unroll
                for (int m = 0; m < 2; ++m) {
                    int row = m * 16 + c;
                    af[m] = *(const bf16x8*)&Xb[(row * 256 + kt * 32 + g * 8) ^ ((row & 7) << 3)];
                }
                #pragma unroll
                for (int m = 0; m < 2; ++m)
                    acc1[m] = MFMA16(af[m], wf1[kt], acc1[m]);
            }
            // issue wf1(ch+2)
            if (ch < 14) {
                #pragma unroll
                for (int kt = 0; kt < 8; ++kt)
                    wf1[kt] = *(const bf16x8*)
                        &w1s[(size_t)((kt * 64 + (ch + 2) * 4 + w) * 64 + lane) * 8];
            }
            float bias = lin1b[(ch + 1) * 64 + w * 16 + c];
            unsigned short* yw = Y1c[(ch + 1) & 1];
            #pragma unroll
            for (int m = 0; m < 2; ++m)
                #pragma unroll
                for (int r = 0; r < 4; ++r) {
                    int row = m * 16 + g * 4 + r;
                    yw[(row * 64 + w * 16 + c) ^ ((row & 7) << 3)] =
                        f2bf_rne(gelu_fast(acc1[m][r] + bias));
                }
        }
        __syncthreads();
    }

    // ---- epilogue: + lin2 bias + h residual (bf16 from Xb), LN2, store ----
    float b2c[4], g2c[4], bb2c[4];
    #pragma unroll
    for (int n = 0; n < 4; ++n) {
        int col = w * 64 + n * 16 + c;
        b2c[n] = lin2b[col]; g2c[n] = ln2g[col]; bb2c[n] = ln2b[col];
    }
    #pragma unroll
    for (int m = 0; m < 2; ++m)
        #pragma unroll
        for (int n = 0; n < 4; ++n)
            #pragma unroll
            for (int r = 0; r < 4; ++r) {
                int row = m * 16 + g * 4 + r;
                int col = w * 64 + n * 16 + c;
                float hres = bf2f(Xb[(row * 256 + col) ^ ((row & 7) << 3)]);
                acc2[m][n][r] += b2c[n] + hres;
            }
    #pragma unroll
    for (int m = 0; m < 2; ++m)
        #pragma unroll
        for (int r = 0; r < 4; ++r) {
            float s = 0.f, s2 = 0.f;
            #pragma unroll
            for (int n = 0; n < 4; ++n) {
                float v = acc2[m][n][r];
                s += v; s2 += v * v;
            }
            #pragma unroll
            for (int mask = 1; mask < 16; mask <<= 1) {
                s  += __shfl_xor(s, mask);
                s2 += __shfl_xor(s2, mask);
            }
            if (c == 0) {
                int row = m * 16 + g * 4 + r;
                psum[0][row][w] = s;
                psum[1][row][w] = s2;
            }
        }
    __syncthreads();
    if (tid < 32) {
        float s  = psum[0][tid][0] + psum[0][tid][1] + psum[0][tid][2] + psum[0][tid][3];
        float s2 = psum[1][tid][0] + psum[1][tid][1] + psum[1][tid][2] + psum[1][tid][3];
        float mn = s * (1.f / D_MODEL);
        float var = s2 * (1.f / D_MODEL) - mn * mn;
        rowm[tid] = mn;
        rowr[tid] = rsqrtf(var + 1e-5f);
    }
    __syncthreads();
    #pragma unroll
    for (int m = 0; m < 2; ++m)
        #pragma unroll
        for (int n = 0; n < 4; ++n)
            #pragma unroll
            for (int r = 0; r < 4; ++r) {
                int row = m * 16 + g * 4 + r;
                int col = w * 64 + n * 16 + c;
                float v = (acc2[m][n][r] - rowm[row]) * rowr[row] * g2c[n] + bb2c[n];
                out[(size_t)(r0 + row) * D_MODEL + col] = v;
            }
}

// ---------------------------------------------------------------------------
extern "C" void kernel_launch(void* const* d_in, const int* in_sizes, int n_in,
                              void* d_out, int out_size, void* d_ws, size_t ws_size,
                              hipStream_t stream) {
    const float* src   = (const float*)d_in[0];
    const float* rp    = (const float*)d_in[1];
    const float* qpe   = (const float*)d_in[2];
    const float* off_w = (const float*)d_in[5];
    const float* off_b = (const float*)d_in[6];
    const float* aw_w  = (const float*)d_in[7];
    const float* aw_b  = (const float*)d_in[8];
    const float* val_w = (const float*)d_in[9];
    const float* val_b = (const float*)d_in[10];
    const float* out_w = (const float*)d_in[11];
    const float* out_b = (const float*)d_in[12];
    const float* w1    = (const float*)d_in[13];
    const float* b1    = (const float*)d_in[14];
    const float* w2    = (const float*)d_in[15];
    const float* b2    = (const float*)d_in[16];
    const float* ln1g  = (const float*)d_in[17];
    const float* ln1b  = (const float*)d_in[18];
    const float* ln2g  = (const float*)d_in[19];
    const float* ln2b  = (const float*)d_in[20];
    float* out = (float*)d_out;

    float* ws    = (float*)d_ws;
    float* value = ws;                                   // M*256 region (bf16 used)
    float* offs  = value + (size_t)M_ROWS * D_MODEL;     // M*192
    float* aw    = offs + (size_t)M_ROWS * NOFF;         // M*96
    float* attn  = aw + (size_t)M_ROWS * NAW;            // M*256 region (bf16 used)
    unsigned short* valueb = (unsigned short*)value;     // [b][h][Lq][32] bf16
    unsigned short* attnb  = (unsigned short*)attn;      // [row][256] bf16
    unsigned short* w1s   = (unsigned short*)(attn + (size_t)M_ROWS * D_MODEL);
    unsigned short* w2s   = w1s + 262144;
    unsigned short* valws = w2s + 262144;                // 65536
    unsigned short* outws = valws + 65536;               // 65536
    unsigned short* qws   = outws + 65536;               // 73728

    k_wprep<<<1024, 256, 0, stream>>>(w1, w2, val_w, out_w, off_w, aw_w,
                                      w1s, w2s, valws, outws, qws);
    k_prep_mfma<<<M_ROWS / 64, 256, 0, stream>>>(src, qpe, valws, val_b,
                                                 qws, off_b, aw_b,
                                                 valueb, offs, aw);
    k_sample<<<M_ROWS / 2, 256, 0, stream>>>(rp, valueb, offs, aw, attnb);
    k_mlp<<<M_ROWS / 32, 256, 0, stream>>>(attnb, src, outws, out_b,
                                           ln1g, ln1b, w1s, b1, w2s, b2,
                                           ln2g, ln2b, out);
}

// Round 14
// 224.070 us; speedup vs baseline: 1.2356x; 1.1248x over previous
//
#include <hip/hip_runtime.h>

#define D_MODEL 256
#define NHEAD 8
#define HEAD_DIM 32
#define LEVELS 3
#define POINTS 4
#define DFF 1024
#define LQ 8400
#define BATCH 4
#define M_ROWS (BATCH * LQ)   /* 33600 */
#define NOFF 192              /* 8*3*4*2 */
#define NAW 96                /* 8*3*4 */

typedef __attribute__((ext_vector_type(8))) short bf16x8;
typedef __attribute__((ext_vector_type(4))) float f32x4;
#define MFMA16(a, b, c) __builtin_amdgcn_mfma_f32_16x16x32_bf16(a, b, c, 0, 0, 0)

// tanh-form gelu: x * sigmoid(1.5957691216*(x + 0.044715 x^3)).
__device__ __forceinline__ float gelu_fast(float x) {
    float u = 1.5957691216f * x * (1.f + 0.044715f * x * x);
    return x / (1.f + __expf(-u));
}

__device__ __forceinline__ unsigned short f2bf_rne(float f) {
    unsigned int u = __float_as_uint(f);
    u += 0x7fff + ((u >> 16) & 1);
    return (unsigned short)(u >> 16);
}

__device__ __forceinline__ float bf2f(unsigned short v) {
    return __uint_as_float(((unsigned)v) << 16);
}

// ---------------------------------------------------------------------------
// Kernel W: convert all GEMM weights f32 -> bf16 in MFMA fragment order.
// ---------------------------------------------------------------------------
__global__ __launch_bounds__(256) void k_wprep(
    const float* __restrict__ w1, const float* __restrict__ w2,
    const float* __restrict__ val_w, const float* __restrict__ out_w,
    const float* __restrict__ off_w, const float* __restrict__ aw_w,
    unsigned short* __restrict__ w1s, unsigned short* __restrict__ w2s,
    unsigned short* __restrict__ valws, unsigned short* __restrict__ outws,
    unsigned short* __restrict__ qws)
{
    int idx = blockIdx.x * 256 + threadIdx.x;   // 0 .. 262143
    int j = idx & 7, lane = (idx >> 3) & 63, rest = idx >> 9;
    int k = (lane >> 4) * 8 + j;
    int cc = lane & 15;
    {   // w1: 256x1024, NT=64
        int nt = rest & 63, kt = rest >> 6;
        w1s[idx] = f2bf_rne(w1[(size_t)(kt * 32 + k) * DFF + nt * 16 + cc]);
    }
    {   // w2: 1024x256, NT=16, KT=32
        int nt = rest & 15, kt = rest >> 4;
        w2s[idx] = f2bf_rne(w2[(size_t)(kt * 32 + k) * D_MODEL + nt * 16 + cc]);
    }
    if (idx < 65536) {   // val_w / out_w: 256x256, NT=16, KT=8
        int nt = rest & 15, kt = rest >> 4;
        valws[idx] = f2bf_rne(val_w[(size_t)(kt * 32 + k) * D_MODEL + nt * 16 + cc]);
        outws[idx] = f2bf_rne(out_w[(size_t)(kt * 32 + k) * D_MODEL + nt * 16 + cc]);
    }
    if (idx < 73728) {   // q-path: 256x288, NT=18, KT=8
        int nt = rest % 18, kt = rest / 18;
        int col = nt * 16 + cc;
        float v = (col < NOFF) ? off_w[(size_t)(kt * 32 + k) * NOFF + col]
                               : aw_w[(size_t)(kt * 32 + k) * NAW + (col - NOFF)];
        qws[idx] = f2bf_rne(v);
    }
}

// ---------------------------------------------------------------------------
// Kernel A (MFMA): value(bf16, head-major) = src@val_w+b; offs = q@off_w+b;
// aw = softmax(q@aw_w+b).  (unchanged from R11)
// ---------------------------------------------------------------------------
__global__ __launch_bounds__(256, 2) void k_prep_mfma(
    const float* __restrict__ src, const float* __restrict__ qpe,
    const unsigned short* __restrict__ valws, const float* __restrict__ val_b,
    const unsigned short* __restrict__ qws, const float* __restrict__ off_b,
    const float* __restrict__ aw_b,
    unsigned short* __restrict__ valueb, float* __restrict__ offs,
    float* __restrict__ aw)
{
    __shared__ unsigned short Xs[64 * 256];
    __shared__ unsigned short Xq[64 * 256];
    float (*awl)[NAW] = (float(*)[NAW])Xs;

    const int tid = threadIdx.x;
    const int w = tid >> 6, lane = tid & 63;
    const int g = lane >> 4, c = lane & 15;
    const int r0 = blockIdx.x * 64;

    for (int i = tid; i < 64 * 32; i += 256) {
        int row = i >> 5, c8 = (i & 31) * 8;
        const float4* ps = (const float4*)(src + (size_t)(r0 + row) * D_MODEL + c8);
        const float4* pq = (const float4*)(qpe + (size_t)(r0 + row) * D_MODEL + c8);
        float4 s0 = ps[0], s1 = ps[1];
        float4 q0 = pq[0], q1 = pq[1];
        q0.x += s0.x; q0.y += s0.y; q0.z += s0.z; q0.w += s0.w;
        q1.x += s1.x; q1.y += s1.y; q1.z += s1.z; q1.w += s1.w;
        uint4 pks, pkq;
        pks.x = (unsigned)f2bf_rne(s0.x) | ((unsigned)f2bf_rne(s0.y) << 16);
        pks.y = (unsigned)f2bf_rne(s0.z) | ((unsigned)f2bf_rne(s0.w) << 16);
        pks.z = (unsigned)f2bf_rne(s1.x) | ((unsigned)f2bf_rne(s1.y) << 16);
        pks.w = (unsigned)f2bf_rne(s1.z) | ((unsigned)f2bf_rne(s1.w) << 16);
        pkq.x = (unsigned)f2bf_rne(q0.x) | ((unsigned)f2bf_rne(q0.y) << 16);
        pkq.y = (unsigned)f2bf_rne(q0.z) | ((unsigned)f2bf_rne(q0.w) << 16);
        pkq.z = (unsigned)f2bf_rne(q1.x) | ((unsigned)f2bf_rne(q1.y) << 16);
        pkq.w = (unsigned)f2bf_rne(q1.z) | ((unsigned)f2bf_rne(q1.w) << 16);
        int di = (row * 256 + c8) ^ ((row & 7) << 3);
        *(uint4*)&Xs[di] = pks;
        *(uint4*)&Xq[di] = pkq;
    }
    __syncthreads();

    const int arow = w * 16 + c;
    const int aidx0 = (arow * 256) ^ ((arow & 7) << 3);

    {   // value GEMM: N=256, batched weight fragments per kt
        f32x4 accv[16];
        #pragma unroll
        for (int nt = 0; nt < 16; ++nt) accv[nt] = (f32x4){0.f, 0.f, 0.f, 0.f};
        #pragma unroll
        for (int kt = 0; kt < 8; ++kt) {
            bf16x8 wv[16];
            #pragma unroll
            for (int nt = 0; nt < 16; ++nt)
                wv[nt] = *(const bf16x8*)&valws[(size_t)((kt * 16 + nt) * 64 + lane) * 8];
            bf16x8 af = *(const bf16x8*)&Xs[aidx0 ^ (kt * 32 + g * 8)];
            #pragma unroll
            for (int nt = 0; nt < 16; ++nt)
                accv[nt] = MFMA16(af, wv[nt], accv[nt]);
        }
        #pragma unroll
        for (int nt = 0; nt < 16; ++nt) {
            float bias = val_b[nt * 16 + c];
            int hh = nt >> 1, dd = (nt & 1) * 16 + c;
            #pragma unroll
            for (int r = 0; r < 4; ++r) {
                int rg = r0 + w * 16 + g * 4 + r;
                int b = rg / LQ, qr = rg - b * LQ;
                valueb[(((size_t)b * NHEAD + hh) * LQ + qr) * HEAD_DIM + dd] =
                    f2bf_rne(accv[nt][r] + bias);
            }
        }
    }
    __syncthreads();

    {   // q GEMM: N=288 (12 offs tiles + 6 aw tiles), batched fragments
        f32x4 accq[18];
        #pragma unroll
        for (int nt = 0; nt < 18; ++nt) accq[nt] = (f32x4){0.f, 0.f, 0.f, 0.f};
        #pragma unroll
        for (int kt = 0; kt < 8; ++kt) {
            bf16x8 wq[18];
            #pragma unroll
            for (int nt = 0; nt < 18; ++nt)
                wq[nt] = *(const bf16x8*)&qws[(size_t)((kt * 18 + nt) * 64 + lane) * 8];
            bf16x8 af = *(const bf16x8*)&Xq[aidx0 ^ (kt * 32 + g * 8)];
            #pragma unroll
            for (int nt = 0; nt < 18; ++nt)
                accq[nt] = MFMA16(af, wq[nt], accq[nt]);
        }
        #pragma unroll
        for (int nt = 0; nt < 12; ++nt) {
            float bias = off_b[nt * 16 + c];
            #pragma unroll
            for (int r = 0; r < 4; ++r) {
                int row = w * 16 + g * 4 + r;
                offs[(size_t)(r0 + row) * NOFF + nt * 16 + c] = accq[nt][r] + bias;
            }
        }
        #pragma unroll
        for (int nt2 = 0; nt2 < 6; ++nt2) {
            float bias = aw_b[nt2 * 16 + c];
            #pragma unroll
            for (int r = 0; r < 4; ++r) {
                int row = w * 16 + g * 4 + r;
                awl[row][nt2 * 16 + c] = accq[nt2 + 12][r] + bias;
            }
        }
    }
    __syncthreads();

    for (int task = tid; task < 64 * NHEAD; task += 256) {
        int row = task >> 3, hh = task & 7;
        const float* p = &awl[row][hh * 12];
        float m = p[0];
        #pragma unroll
        for (int j = 1; j < 12; ++j) m = fmaxf(m, p[j]);
        float e[12];
        float sum = 0.f;
        #pragma unroll
        for (int j = 0; j < 12; ++j) { e[j] = __expf(p[j] - m); sum += e[j]; }
        float inv = 1.f / sum;
        float* o = &aw[(size_t)(r0 + row) * NAW + hh * 12];
        #pragma unroll
        for (int j = 0; j < 12; ++j) o[j] = e[j] * inv;
    }
}

// ---------------------------------------------------------------------------
// Kernel B: deformable bilinear sampling on bf16 head-major value.
// XCD-aware chunked blockIdx swizzle: consecutive LOGICAL blocks (spatially
// nearby queries -> overlapping value reads) land on the SAME XCD's L2.
// grid = 16800, 16800 % 8 == 0 -> simple bijective swizzle.
// ---------------------------------------------------------------------------
__global__ __launch_bounds__(256) void k_sample(
    const float* __restrict__ rp, const unsigned short* __restrict__ valueb,
    const float* __restrict__ offs, const float* __restrict__ aw,
    unsigned short* __restrict__ attnb)
{
    __shared__ int   s_x0[2][NAW];
    __shared__ int   s_y0[2][NAW];
    __shared__ float s_fx[2][NAW];
    __shared__ float s_fy[2][NAW];
    __shared__ float s_w[2][NAW];

    const int tid = threadIdx.x;
    // XCD swizzle: hw round-robins blockIdx%8 across XCDs; give each XCD a
    // contiguous logical range. 16800/8 = 2100 chunks per XCD.
    const int swz = (blockIdx.x & 7) * (M_ROWS / 2 / 8) + (blockIdx.x >> 3);
    const int row0 = swz * 2;

    if (tid < 2 * NAW) {
        int rl = tid / NAW;
        int t  = tid - rl * NAW;
        int row = row0 + rl;
        const int h = t / 12, lp = t % 12, l = lp >> 2, p = lp & 3;
        const int dims[LEVELS] = {80, 40, 20};
        const int Wl = dims[l];
        float refx = rp[((size_t)row * LEVELS + l) * 2 + 0];
        float refy = rp[((size_t)row * LEVELS + l) * 2 + 1];
        size_t obase = (size_t)row * NOFF + (size_t)((h * LEVELS + l) * POINTS + p) * 2;
        float ox = offs[obase + 0];
        float oy = offs[obase + 1];
        float x = refx * (float)Wl + ox - 0.5f;
        float y = refy * (float)Wl + oy - 0.5f;
        float x0f = floorf(x), y0f = floorf(y);
        s_x0[rl][t] = (int)x0f;
        s_y0[rl][t] = (int)y0f;
        s_fx[rl][t] = x - x0f;
        s_fy[rl][t] = y - y0f;
        s_w[rl][t]  = aw[(size_t)row * NAW + t];
    }
    __syncthreads();

    const int rl = tid >> 7;
    const int hh = (tid >> 4) & 7;
    const int dp = tid & 15;
    const int row = row0 + rl;
    const int b = row / LQ;
    const unsigned short* vb =
        valueb + (((size_t)b * NHEAD + hh) * LQ) * HEAD_DIM + dp * 2;
    float accx = 0.f, accy = 0.f;

    #pragma unroll
    for (int lp = 0; lp < 12; ++lp) {
        const int l = lp >> 2;
        const int dims[LEVELS] = {80, 40, 20};
        const int lsis[LEVELS] = {0, 6400, 8000};
        const int W = dims[l], H = dims[l], s = lsis[l];
        const int t = hh * 12 + lp;
        int x0 = s_x0[rl][t], y0 = s_y0[rl][t];
        float fx = s_fx[rl][t], fy = s_fy[rl][t], w = s_w[rl][t];
        float w00 = (1.f - fx) * (1.f - fy);
        float w10 = fx * (1.f - fy);
        float w01 = (1.f - fx) * fy;
        float w11 = fx * fy;
        int x1 = x0 + 1, y1 = y0 + 1;
        bool xv0 = (x0 >= 0) && (x0 < W);
        bool xv1 = (x1 >= 0) && (x1 < W);
        bool yv0 = (y0 >= 0) && (y0 < H);
        bool yv1 = (y1 >= 0) && (y1 < H);
        unsigned u00 = 0, u10 = 0, u01 = 0, u11 = 0;
        if (xv0 && yv0) u00 = *(const unsigned*)&vb[(size_t)(s + y0 * W + x0) * HEAD_DIM];
        if (xv1 && yv0) u10 = *(const unsigned*)&vb[(size_t)(s + y0 * W + x1) * HEAD_DIM];
        if (xv0 && yv1) u01 = *(const unsigned*)&vb[(size_t)(s + y1 * W + x0) * HEAD_DIM];
        if (xv1 && yv1) u11 = *(const unsigned*)&vb[(size_t)(s + y1 * W + x1) * HEAD_DIM];
        float sx = w00 * bf2f((unsigned short)u00) + w10 * bf2f((unsigned short)u10)
                 + w01 * bf2f((unsigned short)u01) + w11 * bf2f((unsigned short)u11);
        float sy = w00 * bf2f((unsigned short)(u00 >> 16)) + w10 * bf2f((unsigned short)(u10 >> 16))
                 + w01 * bf2f((unsigned short)(u01 >> 16)) + w11 * bf2f((unsigned short)(u11 >> 16));
        accx += w * sx;
        accy += w * sy;
    }
    unsigned pk = (unsigned)f2bf_rne(accx) | ((unsigned)f2bf_rne(accy) << 16);
    *(unsigned*)&attnb[(size_t)row * D_MODEL + hh * HEAD_DIM + dp * 2] = pk;
}

// ---------------------------------------------------------------------------
// Kernel M: fused out-proj + LN1 + FFN + LN2.  (R11 verbatim — the measured
// optimum: BM=32, wf1[16]/wf2[16] batched+pipelined, launch_bounds(256,2),
// VGPR 128, no spill, 114.6 us.)
// ---------------------------------------------------------------------------
__global__ __launch_bounds__(256, 2) void k_mlp(
    const unsigned short* __restrict__ attnb, const float* __restrict__ src,
    const unsigned short* __restrict__ outws, const float* __restrict__ out_b,
    const float* __restrict__ ln1g, const float* __restrict__ ln1b,
    const unsigned short* __restrict__ w1s, const float* __restrict__ lin1b,
    const unsigned short* __restrict__ w2s, const float* __restrict__ lin2b,
    const float* __restrict__ ln2g, const float* __restrict__ ln2b,
    float* __restrict__ out)
{
    __shared__ unsigned short Xb[32 * 256];      // 16 KB: attn bf16, then h bf16
    __shared__ unsigned short Y1c[2][32 * 136];  // 17.4 KB double-buffered
    __shared__ float psum[2][32][4];
    __shared__ float rowm[32], rowr[32];

    const int tid = threadIdx.x;
    const int w = tid >> 6, lane = tid & 63;
    const int g = lane >> 4, c = lane & 15;
    const int r0 = blockIdx.x * 32;

    // ---- stage attn (already bf16) -> swizzled LDS ----
    for (int i = tid; i < 32 * 32; i += 256) {
        int row = i >> 5, c8 = (i & 31) * 8;
        uint4 pk = *(const uint4*)&attnb[(size_t)(r0 + row) * D_MODEL + c8];
        int di = (row * 256 + c8) ^ ((row & 7) << 3);
        *(uint4*)&Xb[di] = pk;
    }
    __syncthreads();

    {   // ---- out-proj GEMM (weights in 2 batches of 16) + LN1 -> Xb ----
        f32x4 hacc[2][4];
        #pragma unroll
        for (int m = 0; m < 2; ++m)
            #pragma unroll
            for (int n = 0; n < 4; ++n)
                hacc[m][n] = (f32x4){0.f, 0.f, 0.f, 0.f};

        #pragma unroll
        for (int half = 0; half < 2; ++half) {
            bf16x8 wfa[16];
            #pragma unroll
            for (int kt = 0; kt < 4; ++kt)
                #pragma unroll
                for (int n = 0; n < 4; ++n)
                    wfa[kt * 4 + n] = *(const bf16x8*)
                        &outws[(size_t)(((half * 4 + kt) * 16 + w * 4 + n) * 64 + lane) * 8];
            #pragma unroll
            for (int kt = 0; kt < 4; ++kt) {
                bf16x8 af[2];
                #pragma unroll
                for (int m = 0; m < 2; ++m) {
                    int row = m * 16 + c;
                    af[m] = *(const bf16x8*)
                        &Xb[(row * 256 + (half * 4 + kt) * 32 + g * 8) ^ ((row & 7) << 3)];
                }
                #pragma unroll
                for (int n = 0; n < 4; ++n)
                    #pragma unroll
                    for (int m = 0; m < 2; ++m)
                        hacc[m][n] = MFMA16(af[m], wfa[kt * 4 + n], hacc[m][n]);
            }
        }
        float ob[4], lg[4], lb[4];
        #pragma unroll
        for (int n = 0; n < 4; ++n) {
            int col = w * 64 + n * 16 + c;
            ob[n] = out_b[col]; lg[n] = ln1g[col]; lb[n] = ln1b[col];
        }
        #pragma unroll
        for (int m = 0; m < 2; ++m)
            #pragma unroll
            for (int n = 0; n < 4; ++n)
                #pragma unroll
                for (int r = 0; r < 4; ++r) {
                    int row = m * 16 + g * 4 + r;
                    int col = w * 64 + n * 16 + c;
                    hacc[m][n][r] += ob[n] + src[(size_t)(r0 + row) * D_MODEL + col];
                }
        #pragma unroll
        for (int m = 0; m < 2; ++m)
            #pragma unroll
            for (int r = 0; r < 4; ++r) {
                float s = 0.f, s2 = 0.f;
                #pragma unroll
                for (int n = 0; n < 4; ++n) {
                    float v = hacc[m][n][r];
                    s += v; s2 += v * v;
                }
                #pragma unroll
                for (int mask = 1; mask < 16; mask <<= 1) {
                    s  += __shfl_xor(s, mask);
                    s2 += __shfl_xor(s2, mask);
                }
                if (c == 0) {
                    int row = m * 16 + g * 4 + r;
                    psum[0][row][w] = s;
                    psum[1][row][w] = s2;
                }
            }
        __syncthreads();
        if (tid < 32) {
            float s  = psum[0][tid][0] + psum[0][tid][1] + psum[0][tid][2] + psum[0][tid][3];
            float s2 = psum[1][tid][0] + psum[1][tid][1] + psum[1][tid][2] + psum[1][tid][3];
            float mn = s * (1.f / D_MODEL);
            float var = s2 * (1.f / D_MODEL) - mn * mn;
            rowm[tid] = mn;
            rowr[tid] = rsqrtf(var + 1e-5f);
        }
        __syncthreads();
        #pragma unroll
        for (int m = 0; m < 2; ++m)
            #pragma unroll
            for (int n = 0; n < 4; ++n)
                #pragma unroll
                for (int r = 0; r < 4; ++r) {
                    int row = m * 16 + g * 4 + r;
                    int col = w * 64 + n * 16 + c;
                    float v = (hacc[m][n][r] - rowm[row]) * rowr[row] * lg[n] + lb[n];
                    Xb[(row * 256 + col) ^ ((row & 7) << 3)] = f2bf_rne(v);
                }
    }
    __syncthreads();

    // ---- FFN with batched + pipelined weight fragments ----
    f32x4 acc2[2][4];
    #pragma unroll
    for (int m = 0; m < 2; ++m)
        #pragma unroll
        for (int n = 0; n < 4; ++n)
            acc2[m][n] = (f32x4){0.f, 0.f, 0.f, 0.f};

    bf16x8 wf1[16];   // W1 frags for the NEXT GEMM1 chunk (2/kt x 8kt)
    bf16x8 wf2[16];   // W2 frags for the NEXT GEMM2 chunk (4/kt2 x 4kt2)

    #pragma unroll
    for (int kt = 0; kt < 8; ++kt) {
        wf1[kt * 2 + 0] = *(const bf16x8*)&w1s[(size_t)((kt * 64 + w * 2 + 0) * 64 + lane) * 8];
        wf1[kt * 2 + 1] = *(const bf16x8*)&w1s[(size_t)((kt * 64 + w * 2 + 1) * 64 + lane) * 8];
    }
    {   // GEMM1 chunk 0 -> Y1c[0]
        f32x4 acc1[2][2];
        #pragma unroll
        for (int m = 0; m < 2; ++m) {
            acc1[m][0] = (f32x4){0.f, 0.f, 0.f, 0.f};
            acc1[m][1] = (f32x4){0.f, 0.f, 0.f, 0.f};
        }
        #pragma unroll
        for (int kt = 0; kt < 8; ++kt) {
            bf16x8 af[2];
            #pragma unroll
            for (int m = 0; m < 2; ++m) {
                int row = m * 16 + c;
                af[m] = *(const bf16x8*)&Xb[(row * 256 + kt * 32 + g * 8) ^ ((row & 7) << 3)];
            }
            #pragma unroll
            for (int m = 0; m < 2; ++m) {
                acc1[m][0] = MFMA16(af[m], wf1[kt * 2 + 0], acc1[m][0]);
                acc1[m][1] = MFMA16(af[m], wf1[kt * 2 + 1], acc1[m][1]);
            }
        }
        #pragma unroll
        for (int kt2 = 0; kt2 < 4; ++kt2)
            #pragma unroll
            for (int n = 0; n < 4; ++n)
                wf2[kt2 * 4 + n] = *(const bf16x8*)
                    &w2s[(size_t)(((kt2)*16 + w * 4 + n) * 64 + lane) * 8];
        #pragma unroll
        for (int kt = 0; kt < 8; ++kt) {
            wf1[kt * 2 + 0] = *(const bf16x8*)&w1s[(size_t)((kt * 64 + 8 + w * 2 + 0) * 64 + lane) * 8];
            wf1[kt * 2 + 1] = *(const bf16x8*)&w1s[(size_t)((kt * 64 + 8 + w * 2 + 1) * 64 + lane) * 8];
        }
        float bias0 = lin1b[w * 32 + c];
        float bias1 = lin1b[w * 32 + 16 + c];
        #pragma unroll
        for (int m = 0; m < 2; ++m)
            #pragma unroll
            for (int nt = 0; nt < 2; ++nt)
                #pragma unroll
                for (int r = 0; r < 4; ++r) {
                    int row = m * 16 + g * 4 + r;
                    Y1c[0][row * 136 + w * 32 + nt * 16 + c] =
                        f2bf_rne(gelu_fast(acc1[m][nt][r] + (nt ? bias1 : bias0)));
                }
    }
    __syncthreads();

    for (int nc = 0; nc < 8; ++nc) {
        const unsigned short* yb = Y1c[nc & 1];
        #pragma unroll
        for (int kt2 = 0; kt2 < 4; ++kt2) {
            bf16x8 a2[2];
            #pragma unroll
            for (int m = 0; m < 2; ++m) {
                int row = m * 16 + c;
                a2[m] = *(const bf16x8*)&yb[row * 136 + kt2 * 32 + g * 8];
            }
            #pragma unroll
            for (int n = 0; n < 4; ++n)
                #pragma unroll
                for (int m = 0; m < 2; ++m)
                    acc2[m][n] = MFMA16(a2[m], wf2[kt2 * 4 + n], acc2[m][n]);
        }
        if (nc < 7) {
            #pragma unroll
            for (int kt2 = 0; kt2 < 4; ++kt2)
                #pragma unroll
                for (int n = 0; n < 4; ++n)
                    wf2[kt2 * 4 + n] = *(const bf16x8*)
                        &w2s[(size_t)((((nc + 1) * 4 + kt2) * 16 + w * 4 + n) * 64 + lane) * 8];
            f32x4 acc1[2][2];
            #pragma unroll
            for (int m = 0; m < 2; ++m) {
                acc1[m][0] = (f32x4){0.f, 0.f, 0.f, 0.f};
                acc1[m][1] = (f32x4){0.f, 0.f, 0.f, 0.f};
            }
            #pragma unroll
            for (int kt = 0; kt < 8; ++kt) {
                bf16x8 af[2];
                #pragma unroll
                for (int m = 0; m < 2; ++m) {
                    int row = m * 16 + c;
                    af[m] = *(const bf16x8*)&Xb[(row * 256 + kt * 32 + g * 8) ^ ((row & 7) << 3)];
                }
                #pragma unroll
                for (int m = 0; m < 2; ++m) {
                    acc1[m][0] = MFMA16(af[m], wf1[kt * 2 + 0], acc1[m][0]);
                    acc1[m][1] = MFMA16(af[m], wf1[kt * 2 + 1], acc1[m][1]);
                }
            }
            if (nc < 6) {
                const int ncc = (nc + 2) * 8;
                #pragma unroll
                for (int kt = 0; kt < 8; ++kt) {
                    wf1[kt * 2 + 0] = *(const bf16x8*)
                        &w1s[(size_t)((kt * 64 + ncc + w * 2 + 0) * 64 + lane) * 8];
                    wf1[kt * 2 + 1] = *(const bf16x8*)
                        &w1s[(size_t)((kt * 64 + ncc + w * 2 + 1) * 64 + lane) * 8];
                }
            }
            float bias0 = lin1b[(nc + 1) * 128 + w * 32 + c];
            float bias1 = lin1b[(nc + 1) * 128 + w * 32 + 16 + c];
            unsigned short* yw = Y1c[(nc + 1) & 1];
            #pragma unroll
            for (int m = 0; m < 2; ++m)
                #pragma unroll
                for (int nt = 0; nt < 2; ++nt)
                    #pragma unroll
                    for (int r = 0; r < 4; ++r) {
                        int row = m * 16 + g * 4 + r;
                        yw[row * 136 + w * 32 + nt * 16 + c] =
                            f2bf_rne(gelu_fast(acc1[m][nt][r] + (nt ? bias1 : bias0)));
                    }
        }
        __syncthreads();
    }

    // ---- epilogue: + lin2 bias + h residual (bf16 from Xb), LN2, store ----
    float b2c[4], g2c[4], bb2c[4];
    #pragma unroll
    for (int n = 0; n < 4; ++n) {
        int col = w * 64 + n * 16 + c;
        b2c[n] = lin2b[col]; g2c[n] = ln2g[col]; bb2c[n] = ln2b[col];
    }
    #pragma unroll
    for (int m = 0; m < 2; ++m)
        #pragma unroll
        for (int n = 0; n < 4; ++n)
            #pragma unroll
            for (int r = 0; r < 4; ++r) {
                int row = m * 16 + g * 4 + r;
                int col = w * 64 + n * 16 + c;
                float hres = bf2f(Xb[(row * 256 + col) ^ ((row & 7) << 3)]);
                acc2[m][n][r] += b2c[n] + hres;
            }
    #pragma unroll
    for (int m = 0; m < 2; ++m)
        #pragma unroll
        for (int r = 0; r < 4; ++r) {
            float s = 0.f, s2 = 0.f;
            #pragma unroll
            for (int n = 0; n < 4; ++n) {
                float v = acc2[m][n][r];
                s += v; s2 += v * v;
            }
            #pragma unroll
            for (int mask = 1; mask < 16; mask <<= 1) {
                s  += __shfl_xor(s, mask);
                s2 += __shfl_xor(s2, mask);
            }
            if (c == 0) {
                int row = m * 16 + g * 4 + r;
                psum[0][row][w] = s;
                psum[1][row][w] = s2;
            }
        }
    __syncthreads();
    if (tid < 32) {
        float s  = psum[0][tid][0] + psum[0][tid][1] + psum[0][tid][2] + psum[0][tid][3];
        float s2 = psum[1][tid][0] + psum[1][tid][1] + psum[1][tid][2] + psum[1][tid][3];
        float mn = s * (1.f / D_MODEL);
        float var = s2 * (1.f / D_MODEL) - mn * mn;
        rowm[tid] = mn;
        rowr[tid] = rsqrtf(var + 1e-5f);
    }
    __syncthreads();
    #pragma unroll
    for (int m = 0; m < 2; ++m)
        #pragma unroll
        for (int n = 0; n < 4; ++n)
            #pragma unroll
            for (int r = 0; r < 4; ++r) {
                int row = m * 16 + g * 4 + r;
                int col = w * 64 + n * 16 + c;
                float v = (acc2[m][n][r] - rowm[row]) * rowr[row] * g2c[n] + bb2c[n];
                out[(size_t)(r0 + row) * D_MODEL + col] = v;
            }
}

// ---------------------------------------------------------------------------
extern "C" void kernel_launch(void* const* d_in, const int* in_sizes, int n_in,
                              void* d_out, int out_size, void* d_ws, size_t ws_size,
                              hipStream_t stream) {
    const float* src   = (const float*)d_in[0];
    const float* rp    = (const float*)d_in[1];
    const float* qpe   = (const float*)d_in[2];
    const float* off_w = (const float*)d_in[5];
    const float* off_b = (const float*)d_in[6];
    const float* aw_w  = (const float*)d_in[7];
    const float* aw_b  = (const float*)d_in[8];
    const float* val_w = (const float*)d_in[9];
    const float* val_b = (const float*)d_in[10];
    const float* out_w = (const float*)d_in[11];
    const float* out_b = (const float*)d_in[12];
    const float* w1    = (const float*)d_in[13];
    const float* b1    = (const float*)d_in[14];
    const float* w2    = (const float*)d_in[15];
    const float* b2    = (const float*)d_in[16];
    const float* ln1g  = (const float*)d_in[17];
    const float* ln1b  = (const float*)d_in[18];
    const float* ln2g  = (const float*)d_in[19];
    const float* ln2b  = (const float*)d_in[20];
    float* out = (float*)d_out;

    float* ws    = (float*)d_ws;
    float* value = ws;                                   // M*256 region (bf16 used)
    float* offs  = value + (size_t)M_ROWS * D_MODEL;     // M*192
    float* aw    = offs + (size_t)M_ROWS * NOFF;         // M*96
    float* attn  = aw + (size_t)M_ROWS * NAW;            // M*256 region (bf16 used)
    unsigned short* valueb = (unsigned short*)value;     // [b][h][Lq][32] bf16
    unsigned short* attnb  = (unsigned short*)attn;      // [row][256] bf16
    unsigned short* w1s   = (unsigned short*)(attn + (size_t)M_ROWS * D_MODEL);
    unsigned short* w2s   = w1s + 262144;
    unsigned short* valws = w2s + 262144;                // 65536
    unsigned short* outws = valws + 65536;               // 65536
    unsigned short* qws   = outws + 65536;               // 73728

    k_wprep<<<1024, 256, 0, stream>>>(w1, w2, val_w, out_w, off_w, aw_w,
                                      w1s, w2s, valws, outws, qws);
    k_prep_mfma<<<M_ROWS / 64, 256, 0, stream>>>(src, qpe, valws, val_b,
                                                 qws, off_b, aw_b,
                                                 valueb, offs, aw);
    k_sample<<<M_ROWS / 2, 256, 0, stream>>>(rp, valueb, offs, aw, attnb);
    k_mlp<<<M_ROWS / 32, 256, 0, stream>>>(attnb, src, outws, out_b,
                                           ln1g, ln1b, w1s, b1, w2s, b2,
                                           ln2g, ln2b, out);
}

// Round 16
// 217.692 us; speedup vs baseline: 1.2718x; 1.0293x over previous
//
#include <hip/hip_runtime.h>

#define D_MODEL 256
#define NHEAD 8
#define HEAD_DIM 32
#define LEVELS 3
#define POINTS 4
#define DFF 1024
#define LQ 8400
#define BATCH 4
#define M_ROWS (BATCH * LQ)   /* 33600 */
#define NOFF 192              /* 8*3*4*2 */
#define NAW 96                /* 8*3*4 */

typedef __attribute__((ext_vector_type(8))) short bf16x8;
typedef __attribute__((ext_vector_type(4))) float f32x4;
#define MFMA16(a, b, c) __builtin_amdgcn_mfma_f32_16x16x32_bf16(a, b, c, 0, 0, 0)

// tanh-form gelu: x * sigmoid(1.5957691216*(x + 0.044715 x^3)).
__device__ __forceinline__ float gelu_fast(float x) {
    float u = 1.5957691216f * x * (1.f + 0.044715f * x * x);
    return x / (1.f + __expf(-u));
}

__device__ __forceinline__ unsigned short f2bf_rne(float f) {
    unsigned int u = __float_as_uint(f);
    u += 0x7fff + ((u >> 16) & 1);
    return (unsigned short)(u >> 16);
}

__device__ __forceinline__ float bf2f(unsigned short v) {
    return __uint_as_float(((unsigned)v) << 16);
}

// ---------------------------------------------------------------------------
// Kernel W: convert all GEMM weights f32 -> bf16 in MFMA fragment order.
// ---------------------------------------------------------------------------
__global__ __launch_bounds__(256) void k_wprep(
    const float* __restrict__ w1, const float* __restrict__ w2,
    const float* __restrict__ val_w, const float* __restrict__ out_w,
    const float* __restrict__ off_w, const float* __restrict__ aw_w,
    unsigned short* __restrict__ w1s, unsigned short* __restrict__ w2s,
    unsigned short* __restrict__ valws, unsigned short* __restrict__ outws,
    unsigned short* __restrict__ qws)
{
    int idx = blockIdx.x * 256 + threadIdx.x;   // 0 .. 262143
    int j = idx & 7, lane = (idx >> 3) & 63, rest = idx >> 9;
    int k = (lane >> 4) * 8 + j;
    int cc = lane & 15;
    {   // w1: 256x1024, NT=64
        int nt = rest & 63, kt = rest >> 6;
        w1s[idx] = f2bf_rne(w1[(size_t)(kt * 32 + k) * DFF + nt * 16 + cc]);
    }
    {   // w2: 1024x256, NT=16, KT=32
        int nt = rest & 15, kt = rest >> 4;
        w2s[idx] = f2bf_rne(w2[(size_t)(kt * 32 + k) * D_MODEL + nt * 16 + cc]);
    }
    if (idx < 65536) {   // val_w / out_w: 256x256, NT=16, KT=8
        int nt = rest & 15, kt = rest >> 4;
        valws[idx] = f2bf_rne(val_w[(size_t)(kt * 32 + k) * D_MODEL + nt * 16 + cc]);
        outws[idx] = f2bf_rne(out_w[(size_t)(kt * 32 + k) * D_MODEL + nt * 16 + cc]);
    }
    if (idx < 73728) {   // q-path: 256x288, NT=18, KT=8
        int nt = rest % 18, kt = rest / 18;
        int col = nt * 16 + cc;
        float v = (col < NOFF) ? off_w[(size_t)(kt * 32 + k) * NOFF + col]
                               : aw_w[(size_t)(kt * 32 + k) * NAW + (col - NOFF)];
        qws[idx] = f2bf_rne(v);
    }
}

// ---------------------------------------------------------------------------
// Kernel A (MFMA): value(bf16, head-major) = src@val_w+b; offs = q@off_w+b;
// aw = softmax(q@aw_w+b).  (unchanged)
// ---------------------------------------------------------------------------
__global__ __launch_bounds__(256, 2) void k_prep_mfma(
    const float* __restrict__ src, const float* __restrict__ qpe,
    const unsigned short* __restrict__ valws, const float* __restrict__ val_b,
    const unsigned short* __restrict__ qws, const float* __restrict__ off_b,
    const float* __restrict__ aw_b,
    unsigned short* __restrict__ valueb, float* __restrict__ offs,
    float* __restrict__ aw)
{
    __shared__ unsigned short Xs[64 * 256];
    __shared__ unsigned short Xq[64 * 256];
    float (*awl)[NAW] = (float(*)[NAW])Xs;

    const int tid = threadIdx.x;
    const int w = tid >> 6, lane = tid & 63;
    const int g = lane >> 4, c = lane & 15;
    const int r0 = blockIdx.x * 64;

    for (int i = tid; i < 64 * 32; i += 256) {
        int row = i >> 5, c8 = (i & 31) * 8;
        const float4* ps = (const float4*)(src + (size_t)(r0 + row) * D_MODEL + c8);
        const float4* pq = (const float4*)(qpe + (size_t)(r0 + row) * D_MODEL + c8);
        float4 s0 = ps[0], s1 = ps[1];
        float4 q0 = pq[0], q1 = pq[1];
        q0.x += s0.x; q0.y += s0.y; q0.z += s0.z; q0.w += s0.w;
        q1.x += s1.x; q1.y += s1.y; q1.z += s1.z; q1.w += s1.w;
        uint4 pks, pkq;
        pks.x = (unsigned)f2bf_rne(s0.x) | ((unsigned)f2bf_rne(s0.y) << 16);
        pks.y = (unsigned)f2bf_rne(s0.z) | ((unsigned)f2bf_rne(s0.w) << 16);
        pks.z = (unsigned)f2bf_rne(s1.x) | ((unsigned)f2bf_rne(s1.y) << 16);
        pks.w = (unsigned)f2bf_rne(s1.z) | ((unsigned)f2bf_rne(s1.w) << 16);
        pkq.x = (unsigned)f2bf_rne(q0.x) | ((unsigned)f2bf_rne(q0.y) << 16);
        pkq.y = (unsigned)f2bf_rne(q0.z) | ((unsigned)f2bf_rne(q0.w) << 16);
        pkq.z = (unsigned)f2bf_rne(q1.x) | ((unsigned)f2bf_rne(q1.y) << 16);
        pkq.w = (unsigned)f2bf_rne(q1.z) | ((unsigned)f2bf_rne(q1.w) << 16);
        int di = (row * 256 + c8) ^ ((row & 7) << 3);
        *(uint4*)&Xs[di] = pks;
        *(uint4*)&Xq[di] = pkq;
    }
    __syncthreads();

    const int arow = w * 16 + c;
    const int aidx0 = (arow * 256) ^ ((arow & 7) << 3);

    {   // value GEMM: N=256, batched weight fragments per kt
        f32x4 accv[16];
        #pragma unroll
        for (int nt = 0; nt < 16; ++nt) accv[nt] = (f32x4){0.f, 0.f, 0.f, 0.f};
        #pragma unroll
        for (int kt = 0; kt < 8; ++kt) {
            bf16x8 wv[16];
            #pragma unroll
            for (int nt = 0; nt < 16; ++nt)
                wv[nt] = *(const bf16x8*)&valws[(size_t)((kt * 16 + nt) * 64 + lane) * 8];
            bf16x8 af = *(const bf16x8*)&Xs[aidx0 ^ (kt * 32 + g * 8)];
            #pragma unroll
            for (int nt = 0; nt < 16; ++nt)
                accv[nt] = MFMA16(af, wv[nt], accv[nt]);
        }
        #pragma unroll
        for (int nt = 0; nt < 16; ++nt) {
            float bias = val_b[nt * 16 + c];
            int hh = nt >> 1, dd = (nt & 1) * 16 + c;
            #pragma unroll
            for (int r = 0; r < 4; ++r) {
                int rg = r0 + w * 16 + g * 4 + r;
                int b = rg / LQ, qr = rg - b * LQ;
                valueb[(((size_t)b * NHEAD + hh) * LQ + qr) * HEAD_DIM + dd] =
                    f2bf_rne(accv[nt][r] + bias);
            }
        }
    }
    __syncthreads();

    {   // q GEMM: N=288 (12 offs tiles + 6 aw tiles), batched fragments
        f32x4 accq[18];
        #pragma unroll
        for (int nt = 0; nt < 18; ++nt) accq[nt] = (f32x4){0.f, 0.f, 0.f, 0.f};
        #pragma unroll
        for (int kt = 0; kt < 8; ++kt) {
            bf16x8 wq[18];
            #pragma unroll
            for (int nt = 0; nt < 18; ++nt)
                wq[nt] = *(const bf16x8*)&qws[(size_t)((kt * 18 + nt) * 64 + lane) * 8];
            bf16x8 af = *(const bf16x8*)&Xq[aidx0 ^ (kt * 32 + g * 8)];
            #pragma unroll
            for (int nt = 0; nt < 18; ++nt)
                accq[nt] = MFMA16(af, wq[nt], accq[nt]);
        }
        #pragma unroll
        for (int nt = 0; nt < 12; ++nt) {
            float bias = off_b[nt * 16 + c];
            #pragma unroll
            for (int r = 0; r < 4; ++r) {
                int row = w * 16 + g * 4 + r;
                offs[(size_t)(r0 + row) * NOFF + nt * 16 + c] = accq[nt][r] + bias;
            }
        }
        #pragma unroll
        for (int nt2 = 0; nt2 < 6; ++nt2) {
            float bias = aw_b[nt2 * 16 + c];
            #pragma unroll
            for (int r = 0; r < 4; ++r) {
                int row = w * 16 + g * 4 + r;
                awl[row][nt2 * 16 + c] = accq[nt2 + 12][r] + bias;
            }
        }
    }
    __syncthreads();

    for (int task = tid; task < 64 * NHEAD; task += 256) {
        int row = task >> 3, hh = task & 7;
        const float* p = &awl[row][hh * 12];
        float m = p[0];
        #pragma unroll
        for (int j = 1; j < 12; ++j) m = fmaxf(m, p[j]);
        float e[12];
        float sum = 0.f;
        #pragma unroll
        for (int j = 0; j < 12; ++j) { e[j] = __expf(p[j] - m); sum += e[j]; }
        float inv = 1.f / sum;
        float* o = &aw[(size_t)(r0 + row) * NAW + hh * 12];
        #pragma unroll
        for (int j = 0; j < 12; ++j) o[j] = e[j] * inv;
    }
}

// ---------------------------------------------------------------------------
// Kernel B: deformable bilinear sampling on bf16 head-major value.
// (XCD swizzle kept — measured neutral, zero risk.)
// ---------------------------------------------------------------------------
__global__ __launch_bounds__(256) void k_sample(
    const float* __restrict__ rp, const unsigned short* __restrict__ valueb,
    const float* __restrict__ offs, const float* __restrict__ aw,
    unsigned short* __restrict__ attnb)
{
    __shared__ int   s_x0[2][NAW];
    __shared__ int   s_y0[2][NAW];
    __shared__ float s_fx[2][NAW];
    __shared__ float s_fy[2][NAW];
    __shared__ float s_w[2][NAW];

    const int tid = threadIdx.x;
    const int swz = (blockIdx.x & 7) * (M_ROWS / 2 / 8) + (blockIdx.x >> 3);
    const int row0 = swz * 2;

    if (tid < 2 * NAW) {
        int rl = tid / NAW;
        int t  = tid - rl * NAW;
        int row = row0 + rl;
        const int h = t / 12, lp = t % 12, l = lp >> 2, p = lp & 3;
        const int dims[LEVELS] = {80, 40, 20};
        const int Wl = dims[l];
        float refx = rp[((size_t)row * LEVELS + l) * 2 + 0];
        float refy = rp[((size_t)row * LEVELS + l) * 2 + 1];
        size_t obase = (size_t)row * NOFF + (size_t)((h * LEVELS + l) * POINTS + p) * 2;
        float ox = offs[obase + 0];
        float oy = offs[obase + 1];
        float x = refx * (float)Wl + ox - 0.5f;
        float y = refy * (float)Wl + oy - 0.5f;
        float x0f = floorf(x), y0f = floorf(y);
        s_x0[rl][t] = (int)x0f;
        s_y0[rl][t] = (int)y0f;
        s_fx[rl][t] = x - x0f;
        s_fy[rl][t] = y - y0f;
        s_w[rl][t]  = aw[(size_t)row * NAW + t];
    }
    __syncthreads();

    const int rl = tid >> 7;
    const int hh = (tid >> 4) & 7;
    const int dp = tid & 15;
    const int row = row0 + rl;
    const int b = row / LQ;
    const unsigned short* vb =
        valueb + (((size_t)b * NHEAD + hh) * LQ) * HEAD_DIM + dp * 2;
    float accx = 0.f, accy = 0.f;

    #pragma unroll
    for (int lp = 0; lp < 12; ++lp) {
        const int l = lp >> 2;
        const int dims[LEVELS] = {80, 40, 20};
        const int lsis[LEVELS] = {0, 6400, 8000};
        const int W = dims[l], H = dims[l], s = lsis[l];
        const int t = hh * 12 + lp;
        int x0 = s_x0[rl][t], y0 = s_y0[rl][t];
        float fx = s_fx[rl][t], fy = s_fy[rl][t], w = s_w[rl][t];
        float w00 = (1.f - fx) * (1.f - fy);
        float w10 = fx * (1.f - fy);
        float w01 = (1.f - fx) * fy;
        float w11 = fx * fy;
        int x1 = x0 + 1, y1 = y0 + 1;
        bool xv0 = (x0 >= 0) && (x0 < W);
        bool xv1 = (x1 >= 0) && (x1 < W);
        bool yv0 = (y0 >= 0) && (y0 < H);
        bool yv1 = (y1 >= 0) && (y1 < H);
        unsigned u00 = 0, u10 = 0, u01 = 0, u11 = 0;
        if (xv0 && yv0) u00 = *(const unsigned*)&vb[(size_t)(s + y0 * W + x0) * HEAD_DIM];
        if (xv1 && yv0) u10 = *(const unsigned*)&vb[(size_t)(s + y0 * W + x1) * HEAD_DIM];
        if (xv0 && yv1) u01 = *(const unsigned*)&vb[(size_t)(s + y1 * W + x0) * HEAD_DIM];
        if (xv1 && yv1) u11 = *(const unsigned*)&vb[(size_t)(s + y1 * W + x1) * HEAD_DIM];
        float sx = w00 * bf2f((unsigned short)u00) + w10 * bf2f((unsigned short)u10)
                 + w01 * bf2f((unsigned short)u01) + w11 * bf2f((unsigned short)u11);
        float sy = w00 * bf2f((unsigned short)(u00 >> 16)) + w10 * bf2f((unsigned short)(u10 >> 16))
                 + w01 * bf2f((unsigned short)(u01 >> 16)) + w11 * bf2f((unsigned short)(u11 >> 16));
        accx += w * sx;
        accy += w * sy;
    }
    unsigned pk = (unsigned)f2bf_rne(accx) | ((unsigned)f2bf_rne(accy) << 16);
    *(unsigned*)&attnb[(size_t)row * D_MODEL + hh * HEAD_DIM + dp * 2] = pk;
}

// ---------------------------------------------------------------------------
// Kernel M: fused out-proj + LN1 + FFN + LN2.
// BM=32, CHUNK=64 (wf1[8]+wf2[8]) with UNCAPPED launch_bounds(256,2):
// allocator free to use ~150-170 VGPR -> 3 waves/SIMD -> 3 blocks/CU
// (R13 failed only because (256,3) forced VGPR=84 -> spill).
// Y1c XOR-swizzled stride-64 dbuf (verified R12/R13). 16 chunks, 1 barrier ea.
// ---------------------------------------------------------------------------
__global__ __launch_bounds__(256, 2) void k_mlp(
    const unsigned short* __restrict__ attnb, const float* __restrict__ src,
    const unsigned short* __restrict__ outws, const float* __restrict__ out_b,
    const float* __restrict__ ln1g, const float* __restrict__ ln1b,
    const unsigned short* __restrict__ w1s, const float* __restrict__ lin1b,
    const unsigned short* __restrict__ w2s, const float* __restrict__ lin2b,
    const float* __restrict__ ln2g, const float* __restrict__ ln2b,
    float* __restrict__ out)
{
    __shared__ unsigned short Xb[32 * 256];     // 16 KB: attn bf16, then h bf16
    __shared__ unsigned short Y1c[2][32 * 64];  // 8 KB dbuf, XOR-swizzled
    __shared__ float psum[2][32][4];
    __shared__ float rowm[32], rowr[32];

    const int tid = threadIdx.x;
    const int w = tid >> 6, lane = tid & 63;
    const int g = lane >> 4, c = lane & 15;
    const int r0 = blockIdx.x * 32;

    // ---- stage attn (bf16) -> swizzled LDS ----
    for (int i = tid; i < 32 * 32; i += 256) {
        int row = i >> 5, c8 = (i & 31) * 8;
        uint4 pk = *(const uint4*)&attnb[(size_t)(r0 + row) * D_MODEL + c8];
        int di = (row * 256 + c8) ^ ((row & 7) << 3);
        *(uint4*)&Xb[di] = pk;
    }
    __syncthreads();

    {   // ---- out-proj GEMM (weights in 2 batches of 16) + LN1 -> Xb ----
        f32x4 hacc[2][4];
        #pragma unroll
        for (int m = 0; m < 2; ++m)
            #pragma unroll
            for (int n = 0; n < 4; ++n)
                hacc[m][n] = (f32x4){0.f, 0.f, 0.f, 0.f};

        #pragma unroll
        for (int half = 0; half < 2; ++half) {
            bf16x8 wfa[16];
            #pragma unroll
            for (int kt = 0; kt < 4; ++kt)
                #pragma unroll
                for (int n = 0; n < 4; ++n)
                    wfa[kt * 4 + n] = *(const bf16x8*)
                        &outws[(size_t)(((half * 4 + kt) * 16 + w * 4 + n) * 64 + lane) * 8];
            #pragma unroll
            for (int kt = 0; kt < 4; ++kt) {
                bf16x8 af[2];
                #pragma unroll
                for (int m = 0; m < 2; ++m) {
                    int row = m * 16 + c;
                    af[m] = *(const bf16x8*)
                        &Xb[(row * 256 + (half * 4 + kt) * 32 + g * 8) ^ ((row & 7) << 3)];
                }
                #pragma unroll
                for (int n = 0; n < 4; ++n)
                    #pragma unroll
                    for (int m = 0; m < 2; ++m)
                        hacc[m][n] = MFMA16(af[m], wfa[kt * 4 + n], hacc[m][n]);
            }
        }
        float ob[4], lg[4], lb[4];
        #pragma unroll
        for (int n = 0; n < 4; ++n) {
            int col = w * 64 + n * 16 + c;
            ob[n] = out_b[col]; lg[n] = ln1g[col]; lb[n] = ln1b[col];
        }
        #pragma unroll
        for (int m = 0; m < 2; ++m)
            #pragma unroll
            for (int n = 0; n < 4; ++n)
                #pragma unroll
                for (int r = 0; r < 4; ++r) {
                    int row = m * 16 + g * 4 + r;
                    int col = w * 64 + n * 16 + c;
                    hacc[m][n][r] += ob[n] + src[(size_t)(r0 + row) * D_MODEL + col];
                }
        #pragma unroll
        for (int m = 0; m < 2; ++m)
            #pragma unroll
            for (int r = 0; r < 4; ++r) {
                float s = 0.f, s2 = 0.f;
                #pragma unroll
                for (int n = 0; n < 4; ++n) {
                    float v = hacc[m][n][r];
                    s += v; s2 += v * v;
                }
                #pragma unroll
                for (int mask = 1; mask < 16; mask <<= 1) {
                    s  += __shfl_xor(s, mask);
                    s2 += __shfl_xor(s2, mask);
                }
                if (c == 0) {
                    int row = m * 16 + g * 4 + r;
                    psum[0][row][w] = s;
                    psum[1][row][w] = s2;
                }
            }
        __syncthreads();
        if (tid < 32) {
            float s  = psum[0][tid][0] + psum[0][tid][1] + psum[0][tid][2] + psum[0][tid][3];
            float s2 = psum[1][tid][0] + psum[1][tid][1] + psum[1][tid][2] + psum[1][tid][3];
            float mn = s * (1.f / D_MODEL);
            float var = s2 * (1.f / D_MODEL) - mn * mn;
            rowm[tid] = mn;
            rowr[tid] = rsqrtf(var + 1e-5f);
        }
        __syncthreads();
        #pragma unroll
        for (int m = 0; m < 2; ++m)
            #pragma unroll
            for (int n = 0; n < 4; ++n)
                #pragma unroll
                for (int r = 0; r < 4; ++r) {
                    int row = m * 16 + g * 4 + r;
                    int col = w * 64 + n * 16 + c;
                    float v = (hacc[m][n][r] - rowm[row]) * rowr[row] * lg[n] + lb[n];
                    Xb[(row * 256 + col) ^ ((row & 7) << 3)] = f2bf_rne(v);
                }
    }
    __syncthreads();

    // ---- FFN: 16 chunks of 64 cols, wf1[8]/wf2[8], 1 barrier/chunk ----
    f32x4 acc2[2][4];
    #pragma unroll
    for (int m = 0; m < 2; ++m)
        #pragma unroll
        for (int n = 0; n < 4; ++n)
            acc2[m][n] = (f32x4){0.f, 0.f, 0.f, 0.f};

    bf16x8 wf1[8];   // W1 frags: kt 0..7, nt = ch*4 + w
    bf16x8 wf2[8];   // W2 frags: kt2 0..1 (global ch*2+kt2), n = w*4..+4

    #pragma unroll
    for (int kt = 0; kt < 8; ++kt)
        wf1[kt] = *(const bf16x8*)&w1s[(size_t)((kt * 64 + w) * 64 + lane) * 8];
    {   // GEMM1 chunk 0 -> Y1c[0]
        f32x4 acc1[2];
        #pragma unroll
        for (int m = 0; m < 2; ++m) acc1[m] = (f32x4){0.f, 0.f, 0.f, 0.f};
        #pragma unroll
        for (int kt = 0; kt < 8; ++kt) {
            bf16x8 af[2];
            #pragma unroll
            for (int m = 0; m < 2; ++m) {
                int row = m * 16 + c;
                af[m] = *(const bf16x8*)&Xb[(row * 256 + kt * 32 + g * 8) ^ ((row & 7) << 3)];
            }
            #pragma unroll
            for (int m = 0; m < 2; ++m)
                acc1[m] = MFMA16(af[m], wf1[kt], acc1[m]);
        }
        // issue wf2(0) and wf1(1) — land under gelu + barrier
        #pragma unroll
        for (int kt2 = 0; kt2 < 2; ++kt2)
            #pragma unroll
            for (int n = 0; n < 4; ++n)
                wf2[kt2 * 4 + n] = *(const bf16x8*)
                    &w2s[(size_t)((kt2 * 16 + w * 4 + n) * 64 + lane) * 8];
        #pragma unroll
        for (int kt = 0; kt < 8; ++kt)
            wf1[kt] = *(const bf16x8*)&w1s[(size_t)((kt * 64 + 4 + w) * 64 + lane) * 8];
        float bias = lin1b[w * 16 + c];
        #pragma unroll
        for (int m = 0; m < 2; ++m)
            #pragma unroll
            for (int r = 0; r < 4; ++r) {
                int row = m * 16 + g * 4 + r;
                Y1c[0][(row * 64 + w * 16 + c) ^ ((row & 7) << 3)] =
                    f2bf_rne(gelu_fast(acc1[m][r] + bias));
            }
    }
    __syncthreads();

    for (int ch = 0; ch < 16; ++ch) {
        // GEMM2(ch): W2 rows [ch*64,+64) -> acc2
        const unsigned short* yb = Y1c[ch & 1];
        #pragma unroll
        for (int kt2 = 0; kt2 < 2; ++kt2) {
            bf16x8 a2[2];
            #pragma unroll
            for (int m = 0; m < 2; ++m) {
                int row = m * 16 + c;
                a2[m] = *(const bf16x8*)&yb[(row * 64 + kt2 * 32 + g * 8) ^ ((row & 7) << 3)];
            }
            #pragma unroll
            for (int n = 0; n < 4; ++n)
                #pragma unroll
                for (int m = 0; m < 2; ++m)
                    acc2[m][n] = MFMA16(a2[m], wf2[kt2 * 4 + n], acc2[m][n]);
        }
        if (ch < 15) {
            // issue wf2(ch+1) — after its last use above
            #pragma unroll
            for (int kt2 = 0; kt2 < 2; ++kt2)
                #pragma unroll
                for (int n = 0; n < 4; ++n)
                    wf2[kt2 * 4 + n] = *(const bf16x8*)
                        &w2s[(size_t)((((ch + 1) * 2 + kt2) * 16 + w * 4 + n) * 64 + lane) * 8];
            // GEMM1(ch+1) using wf1 (issued previous iteration)
            f32x4 acc1[2];
            #pragma unroll
            for (int m = 0; m < 2; ++m) acc1[m] = (f32x4){0.f, 0.f, 0.f, 0.f};
            #pragma unroll
            for (int kt = 0; kt < 8; ++kt) {
                bf16x8 af[2];
                #pragma unroll
                for (int m = 0; m < 2; ++m) {
                    int row = m * 16 + c;
                    af[m] = *(const bf16x8*)&Xb[(row * 256 + kt * 32 + g * 8) ^ ((row & 7) << 3)];
                }
                #pragma unroll
                for (int m = 0; m < 2; ++m)
                    acc1[m] = MFMA16(af[m], wf1[kt], acc1[m]);
            }
            // issue wf1(ch+2)
            if (ch < 14) {
                #pragma unroll
                for (int kt = 0; kt < 8; ++kt)
                    wf1[kt] = *(const bf16x8*)
                        &w1s[(size_t)((kt * 64 + (ch + 2) * 4 + w) * 64 + lane) * 8];
            }
            float bias = lin1b[(ch + 1) * 64 + w * 16 + c];
            unsigned short* yw = Y1c[(ch + 1) & 1];
            #pragma unroll
            for (int m = 0; m < 2; ++m)
                #pragma unroll
                for (int r = 0; r < 4; ++r) {
                    int row = m * 16 + g * 4 + r;
                    yw[(row * 64 + w * 16 + c) ^ ((row & 7) << 3)] =
                        f2bf_rne(gelu_fast(acc1[m][r] + bias));
                }
        }
        __syncthreads();
    }

    // ---- epilogue: + lin2 bias + h residual (bf16 from Xb), LN2, store ----
    float b2c[4], g2c[4], bb2c[4];
    #pragma unroll
    for (int n = 0; n < 4; ++n) {
        int col = w * 64 + n * 16 + c;
        b2c[n] = lin2b[col]; g2c[n] = ln2g[col]; bb2c[n] = ln2b[col];
    }
    #pragma unroll
    for (int m = 0; m < 2; ++m)
        #pragma unroll
        for (int n = 0; n < 4; ++n)
            #pragma unroll
            for (int r = 0; r < 4; ++r) {
                int row = m * 16 + g * 4 + r;
                int col = w * 64 + n * 16 + c;
                float hres = bf2f(Xb[(row * 256 + col) ^ ((row & 7) << 3)]);
                acc2[m][n][r] += b2c[n] + hres;
            }
    #pragma unroll
    for (int m = 0; m < 2; ++m)
        #pragma unroll
        for (int r = 0; r < 4; ++r) {
            float s = 0.f, s2 = 0.f;
            #pragma unroll
            for (int n = 0; n < 4; ++n) {
                float v = acc2[m][n][r];
                s += v; s2 += v * v;
            }
            #pragma unroll
            for (int mask = 1; mask < 16; mask <<= 1) {
                s  += __shfl_xor(s, mask);
                s2 += __shfl_xor(s2, mask);
            }
            if (c == 0) {
                int row = m * 16 + g * 4 + r;
                psum[0][row][w] = s;
                psum[1][row][w] = s2;
            }
        }
    __syncthreads();
    if (tid < 32) {
        float s  = psum[0][tid][0] + psum[0][tid][1] + psum[0][tid][2] + psum[0][tid][3];
        float s2 = psum[1][tid][0] + psum[1][tid][1] + psum[1][tid][2] + psum[1][tid][3];
        float mn = s * (1.f / D_MODEL);
        float var = s2 * (1.f / D_MODEL) - mn * mn;
        rowm[tid] = mn;
        rowr[tid] = rsqrtf(var + 1e-5f);
    }
    __syncthreads();
    #pragma unroll
    for (int m = 0; m < 2; ++m)
        #pragma unroll
        for (int n = 0; n < 4; ++n)
            #pragma unroll
            for (int r = 0; r < 4; ++r) {
                int row = m * 16 + g * 4 + r;
                int col = w * 64 + n * 16 + c;
                float v = (acc2[m][n][r] - rowm[row]) * rowr[row] * g2c[n] + bb2c[n];
                out[(size_t)(r0 + row) * D_MODEL + col] = v;
            }
}

// ---------------------------------------------------------------------------
extern "C" void kernel_launch(void* const* d_in, const int* in_sizes, int n_in,
                              void* d_out, int out_size, void* d_ws, size_t ws_size,
                              hipStream_t stream) {
    const float* src   = (const float*)d_in[0];
    const float* rp    = (const float*)d_in[1];
    const float* qpe   = (const float*)d_in[2];
    const float* off_w = (const float*)d_in[5];
    const float* off_b = (const float*)d_in[6];
    const float* aw_w  = (const float*)d_in[7];
    const float* aw_b  = (const float*)d_in[8];
    const float* val_w = (const float*)d_in[9];
    const float* val_b = (const float*)d_in[10];
    const float* out_w = (const float*)d_in[11];
    const float* out_b = (const float*)d_in[12];
    const float* w1    = (const float*)d_in[13];
    const float* b1    = (const float*)d_in[14];
    const float* w2    = (const float*)d_in[15];
    const float* b2    = (const float*)d_in[16];
    const float* ln1g  = (const float*)d_in[17];
    const float* ln1b  = (const float*)d_in[18];
    const float* ln2g  = (const float*)d_in[19];
    const float* ln2b  = (const float*)d_in[20];
    float* out = (float*)d_out;

    float* ws    = (float*)d_ws;
    float* value = ws;                                   // M*256 region (bf16 used)
    float* offs  = value + (size_t)M_ROWS * D_MODEL;     // M*192
    float* aw    = offs + (size_t)M_ROWS * NOFF;         // M*96
    float* attn  = aw + (size_t)M_ROWS * NAW;            // M*256 region (bf16 used)
    unsigned short* valueb = (unsigned short*)value;     // [b][h][Lq][32] bf16
    unsigned short* attnb  = (unsigned short*)attn;      // [row][256] bf16
    unsigned short* w1s   = (unsigned short*)(attn + (size_t)M_ROWS * D_MODEL);
    unsigned short* w2s   = w1s + 262144;
    unsigned short* valws = w2s + 262144;                // 65536
    unsigned short* outws = valws + 65536;               // 65536
    unsigned short* qws   = outws + 65536;               // 73728

    k_wprep<<<1024, 256, 0, stream>>>(w1, w2, val_w, out_w, off_w, aw_w,
                                      w1s, w2s, valws, outws, qws);
    k_prep_mfma<<<M_ROWS / 64, 256, 0, stream>>>(src, qpe, valws, val_b,
                                                 qws, off_b, aw_b,
                                                 valueb, offs, aw);
    k_sample<<<M_ROWS / 2, 256, 0, stream>>>(rp, valueb, offs, aw, attnb);
    k_mlp<<<M_ROWS / 32, 256, 0, stream>>>(attnb, src, outws, out_b,
                                           ln1g, ln1b, w1s, b1, w2s, b2,
                                           ln2g, ln2b, out);
}